// Round 2
// baseline (425.358 us; speedup 1.0000x reference)
//
#include <hip/hip_runtime.h>

typedef unsigned short ushort_t;
typedef __attribute__((ext_vector_type(8))) short short8;
typedef __attribute__((ext_vector_type(4))) float f32x4;

#define Bb 2
#define Ss 2048
#define HID 2048
#define NH 16
#define NKV 4
#define Dd 128
constexpr float EPS_ = 1e-6f;
constexpr float THETA_ = 1000000.0f;
constexpr float SCALE_ = 0.08838834764831845f; // 128^-0.5
constexpr float C2_ = 0.12753785f;             // SCALE * log2(e)
constexpr float THR_RAW_ = 23.5f;              // 3 / C2_: defer-max threshold (P <= 8)

__device__ __forceinline__ ushort_t f2bf(float x) {
  union { float f; unsigned u; } v; v.f = x;
  unsigned r = (v.u + 0x7fffu + ((v.u >> 16) & 1u)) >> 16;
  return (ushort_t)r;
}
__device__ __forceinline__ float bf2f(ushort_t u) {
  union { unsigned u; float f; } v; v.u = ((unsigned)u) << 16;
  return v.f;
}

typedef const __attribute__((address_space(1))) void* gas1_t;
typedef __attribute__((address_space(3))) void* las3_t;
__device__ __forceinline__ void gload_lds16(const void* g, void* l) {
  __builtin_amdgcn_global_load_lds((gas1_t)g, (las3_t)l, 16, 0, 0);
}

__device__ __forceinline__ void store_out(float* p, float v) { *p = v; }
__device__ __forceinline__ void store_out(ushort_t* p, float v) { *p = f2bf(v); }

// ---------------- fp32 -> bf16 straight convert ----------------
__global__ __launch_bounds__(256) void convert_f32_bf16(
    const float* __restrict__ src, ushort_t* __restrict__ dst, long n) {
  long i = ((long)blockIdx.x * 256 + threadIdx.x) * 4;
  if (i + 3 < n) {
    float4 v = *(const float4*)(src + i);
    ushort_t o0 = f2bf(v.x), o1 = f2bf(v.y), o2 = f2bf(v.z), o3 = f2bf(v.w);
    ushort_t* d = dst + i;
    d[0] = o0; d[1] = o1; d[2] = o2; d[3] = o3;
  }
}

// ---------------- fp32 (R x C) -> bf16 transposed (C x R) ----------------
__global__ __launch_bounds__(256) void transpose_f32_bf16(
    const float* __restrict__ src, ushort_t* __restrict__ dst, int R, int C) {
  __shared__ float tile[32][33];
  int c0 = blockIdx.x * 32, r0 = blockIdx.y * 32;
  int tx = threadIdx.x & 31, ty = threadIdx.x >> 5; // ty 0..7
#pragma unroll
  for (int j = 0; j < 4; j++)
    tile[ty + j * 8][tx] = src[(long)(r0 + ty + j * 8) * C + c0 + tx];
  __syncthreads();
#pragma unroll
  for (int j = 0; j < 4; j++)
    dst[(long)(c0 + ty + j * 8) * R + r0 + tx] = f2bf(tile[tx][ty + j * 8]);
}

// ---------------- bf16 GEMM: C[M,N] = A[M,K] * Bt[N,K]^T ----------------
// m97 recipe: 128x128x32 tiles, 4 waves each 64x64, global_load_lds width 16.
template <typename OutT>
__global__ __launch_bounds__(256) void gemm_bt(
    const ushort_t* __restrict__ A, const ushort_t* __restrict__ Bt,
    OutT* __restrict__ C, int M, int N, int K) {
  __shared__ __align__(16) ushort_t As[128 * 32];
  __shared__ __align__(16) ushort_t Bs[128 * 32];
  const int t = threadIdx.x;
  const int wave = t >> 6, lane = t & 63;
  const int wr = wave >> 1, wc = wave & 1;
  const int quad = lane >> 4, l16 = lane & 15;
  const long bm = (long)blockIdx.y * 128, bn = (long)blockIdx.x * 128;

  f32x4 acc[4][4] = {};

  const int srow = t >> 2, schunk = t & 3;
  const ushort_t* aSrc = A + (bm + srow) * (long)K + schunk * 8;
  const ushort_t* bSrc = Bt + (bn + srow) * (long)K + schunk * 8;
  const int ldsOff = srow * 32 + schunk * 8;

  for (int k0 = 0; k0 < K; k0 += 32) {
    __syncthreads();
    gload_lds16(aSrc + k0, &As[ldsOff]);
    gload_lds16(aSrc + (long)64 * K + k0, &As[ldsOff + 64 * 32]);
    gload_lds16(bSrc + k0, &Bs[ldsOff]);
    gload_lds16(bSrc + (long)64 * K + k0, &Bs[ldsOff + 64 * 32]);
    __syncthreads();
    short8 af[4], bf[4];
#pragma unroll
    for (int i = 0; i < 4; i++) {
      af[i] = *(const short8*)&As[(wr * 64 + i * 16 + l16) * 32 + quad * 8];
      bf[i] = *(const short8*)&Bs[(wc * 64 + i * 16 + l16) * 32 + quad * 8];
    }
#pragma unroll
    for (int i = 0; i < 4; i++)
#pragma unroll
      for (int j = 0; j < 4; j++)
        acc[i][j] = __builtin_amdgcn_mfma_f32_16x16x32_bf16(af[i], bf[j], acc[i][j], 0, 0, 0);
  }
#pragma unroll
  for (int i = 0; i < 4; i++)
#pragma unroll
    for (int j = 0; j < 4; j++)
#pragma unroll
      for (int r = 0; r < 4; r++) {
        long rr = bm + wr * 64 + i * 16 + quad * 4 + r;
        long cc = bn + wc * 64 + j * 16 + l16;
        store_out(&C[rr * N + cc], acc[i][j][r]);
      }
}

// ---------------- RMSNorm + RoPE, in place on bf16 qkv ----------------
__global__ __launch_bounds__(256) void rmsnorm_rope(
    ushort_t* __restrict__ qkv, const int* __restrict__ positions,
    const float* __restrict__ qw, const float* __restrict__ kw) {
  int gw = blockIdx.x * 4 + (threadIdx.x >> 6);
  int lane = threadIdx.x & 63;
  int bs = gw / 20, h = gw % 20;
  ushort_t* src = qkv + (long)bs * 3072 + h * 128;
  float x0 = bf2f(src[lane]), x1 = bf2f(src[lane + 64]);
  float ss = x0 * x0 + x1 * x1;
#pragma unroll
  for (int off = 32; off; off >>= 1) ss += __shfl_xor(ss, off);
  float r = rsqrtf(ss * (1.0f / 128.0f) + EPS_);
  const float* w = (h < 16) ? qw : kw;
  x0 = x0 * r * w[lane];
  x1 = x1 * r * w[lane + 64];
  float pos = (float)positions[bs];
  float inv_freq = powf(THETA_, -(float)lane * (1.0f / 64.0f));
  float f = pos * inv_freq;
  float sn, cs;
  sincosf(f, &sn, &cs);
  float o0 = x0 * cs - x1 * sn;
  float o1 = x1 * cs + x0 * sn;
  src[lane] = f2bf(o0);
  src[lane + 64] = f2bf(o1);
}

// ------ V transpose: qkv [B,S,3072] v-columns -> Vt [B,NKV,D,S] ------
__global__ __launch_bounds__(256) void transpose_v(
    const ushort_t* __restrict__ qkv, ushort_t* __restrict__ Vt) {
  __shared__ ushort_t tile[64][65];
  int bh = blockIdx.z; // b*NKV + hk
  int s0 = blockIdx.x * 64, d0 = blockIdx.y * 64;
  int b = bh >> 2, hk = bh & 3;
  int tx = threadIdx.x & 63, ty = threadIdx.x >> 6; // ty 0..3
#pragma unroll
  for (int j = 0; j < 16; j++) {
    int sl = j * 4 + ty;
    tile[sl][tx] = qkv[(long)(b * Ss + s0 + sl) * 3072 + 2560 + hk * 128 + d0 + tx];
  }
  __syncthreads();
  const long vtbase = (long)bh * Dd * Ss;
#pragma unroll
  for (int j = 0; j < 16; j++) {
    int dl = j * 4 + ty;
    Vt[vtbase + (long)(d0 + dl) * Ss + s0 + tx] = tile[tx][dl];
  }
}

// ---------------- flash attention ----------------
// grid (S/128, NH, B); 512 threads = 8 waves; wave w owns Q rows
// [qt*128 + w*16, +16). Double-buffered K/V staging (R1).
// R2 VALU diet (counters: VALUBusy 38% vs MfmaUtil 20% -> softmax chain
// is the bottleneck, not memory):
//  - per-lane l accumulation; cross-lane l reduce ONCE in epilogue
//    (removes 16 shuffle+16 add per kt iteration)
//  - defer-max (T13, THR=3 log2-units, P<=8): skip O-rescale when the
//    tile max doesn't grow; skips the 32-mul rescale most iterations
//  - P-pack stores interleaved with exp2 loop (drain under softmax)
//  - s_setprio(1) around MFMA clusters (T5)
__global__ __launch_bounds__(512) void flash_attn(
    const ushort_t* __restrict__ qkv, const ushort_t* __restrict__ Vt,
    ushort_t* __restrict__ ctx) {
  __shared__ __align__(16) ushort_t Ks[2][64 * 128];   // [kvrow][d] (16 chunks/row)
  __shared__ __align__(16) ushort_t Vs[2][128 * 64];   // [d][kv]    (8 chunks/row)
  __shared__ __align__(16) ushort_t Ps[8][16 * 64];    // per-wave P (8 chunks/row)
  const int qt = blockIdx.x, h = blockIdx.y, b = blockIdx.z;
  const int hk = h >> 2;
  const int t = threadIdx.x, wave = t >> 6, lane = t & 63;
  const int quad = lane >> 4, l16 = lane & 15;

  const ushort_t* qp = qkv + (long)(b * Ss + qt * 128) * 3072 + h * 128;
  const ushort_t* kp = qkv + (long)(b * Ss) * 3072 + 2048 + hk * 128;
  const ushort_t* vp = Vt + ((long)(b * NKV + hk) * Dd) * Ss;

  // staging: issue 4 global_load_lds (2 K-chunks + 2 V-chunks) for tile kt
  auto stage = [&](int kt, int bi) {
    const int k0 = kt * 64;
#pragma unroll
    for (int it = 0; it < 2; it++) {
      int tt = t + it * 512;
      int row = tt >> 4, cl = tt & 15, cg = cl ^ (row & 15);
      gload_lds16(kp + (long)(k0 + row) * 3072 + cg * 8, &Ks[bi][tt * 8]);
    }
#pragma unroll
    for (int it = 0; it < 2; it++) {
      int tt = t + it * 512;
      int row = tt >> 3, cl = tt & 7, cg = cl ^ (row & 7);
      gload_lds16(vp + (long)row * Ss + k0 + cg * 8, &Vs[bi][tt * 8]);
    }
  };

  // prologue: stage tile 0 into buf 0; Q-fragment loads fly alongside
  stage(0, 0);

  // Q A-fragments straight to registers.
  short8 qf[4];
  {
    const ushort_t* qrow = qp + (long)(wave * 16 + l16) * 3072 + quad * 8;
#pragma unroll
    for (int kc = 0; kc < 4; kc++)
      qf[kc] = *(const short8*)(qrow + kc * 32);
  }

  float m_i[4] = {-1e30f, -1e30f, -1e30f, -1e30f};
  float l_acc[4] = {0.f, 0.f, 0.f, 0.f}; // per-lane partial; reduced in epilogue
  f32x4 o[8] = {};

  asm volatile("s_waitcnt vmcnt(0)" ::: "memory");
  __syncthreads();

  int cur = 0;
  for (int kt = 0; kt < Ss / 64; kt++) {
    // issue next tile's loads into the other buffer; latency hides under
    // this tile's compute. No vmcnt wait until the end-of-iter barrier.
    if (kt + 1 < Ss / 64) stage(kt + 1, cur ^ 1);

    // S = Q K^T (16x64 per wave), raw units
    f32x4 sa[4] = {};
    __builtin_amdgcn_s_setprio(1);
#pragma unroll
    for (int kc = 0; kc < 4; kc++) {
#pragma unroll
      for (int nt = 0; nt < 4; nt++) {
        int brow = nt * 16 + l16;
        short8 bfr = *(const short8*)&Ks[cur][brow * 128 + (((kc * 4 + quad) ^ (brow & 15)) * 8)];
        sa[nt] = __builtin_amdgcn_mfma_f32_16x16x32_bf16(qf[kc], bfr, sa[nt], 0, 0, 0);
      }
    }
    __builtin_amdgcn_s_setprio(0);

    // online softmax with defer-max: keep old running max unless the tile
    // max exceeds it by >THR_RAW (then P <= 2^3, safe for bf16/f32 accum).
    float mc[4], alpha[4];
    bool upd[4];
#pragma unroll
    for (int r = 0; r < 4; r++) {
      float mx = fmaxf(fmaxf(sa[0][r], sa[1][r]), fmaxf(sa[2][r], sa[3][r]));
#pragma unroll
      for (int off = 8; off; off >>= 1) mx = fmaxf(mx, __shfl_xor(mx, off));
      float g = mx - m_i[r];
      upd[r] = g > THR_RAW_;
      // exp2 computed unconditionally; selected out when !upd
      float a = __builtin_amdgcn_exp2f((m_i[r] - mx) * C2_);
      alpha[r] = upd[r] ? a : 1.0f;
      m_i[r] = upd[r] ? mx : m_i[r];
      mc[r] = m_i[r] * C2_;
    }
    // P = exp2(S*C2 - mc), pack to LDS immediately (stores drain under the
    // rest of the softmax work); per-lane row-sum only (no shuffles here).
    float rs[4] = {0.f, 0.f, 0.f, 0.f};
#pragma unroll
    for (int nt = 0; nt < 4; nt++)
#pragma unroll
      for (int r = 0; r < 4; r++) {
        float p = __builtin_amdgcn_exp2f(__builtin_fmaf(sa[nt][r], C2_, -mc[r]));
        rs[r] += p;
        int row = quad * 4 + r, col = nt * 16 + l16;
        int cg = col >> 3, ci = col & 7;
        int cl = cg ^ (row & 7);
        union { float f; unsigned u; } pv; pv.f = p;
        Ps[wave][row * 64 + cl * 8 + ci] = (ushort_t)((pv.u + 0x8000u) >> 16);
      }
#pragma unroll
    for (int r = 0; r < 4; r++) l_acc[r] = l_acc[r] * alpha[r] + rs[r];
    // rescale O only when some row's max actually moved (defer-max)
    if (upd[0] | upd[1] | upd[2] | upd[3]) {
#pragma unroll
      for (int dt = 0; dt < 8; dt++)
#pragma unroll
        for (int r = 0; r < 4; r++) o[dt][r] *= alpha[r];
    }
    asm volatile("s_waitcnt lgkmcnt(0)" ::: "memory");
    // O += P V
    __builtin_amdgcn_s_setprio(1);
#pragma unroll
    for (int kc = 0; kc < 2; kc++) {
      int arow = l16;
      short8 af = *(const short8*)&Ps[wave][arow * 64 + (((kc * 4 + quad) ^ (arow & 7)) * 8)];
#pragma unroll
      for (int dt = 0; dt < 8; dt++) {
        int brow = dt * 16 + l16;
        short8 bfr = *(const short8*)&Vs[cur][brow * 64 + (((kc * 4 + quad) ^ (brow & 7)) * 8)];
        o[dt] = __builtin_amdgcn_mfma_f32_16x16x32_bf16(af, bfr, o[dt], 0, 0, 0);
      }
    }
    __builtin_amdgcn_s_setprio(0);

    // publish next tile (vmcnt drain) + protect this buffer until all
    // waves' reads are done (barrier). One sync point per tile.
    asm volatile("s_waitcnt vmcnt(0)" ::: "memory");
    __syncthreads();
    cur ^= 1;
  }
  // epilogue: single cross-lane l reduce, then O /= l, write ctx [B*S, NH*D]
#pragma unroll
  for (int r = 0; r < 4; r++) {
#pragma unroll
    for (int off = 8; off; off >>= 1) l_acc[r] += __shfl_xor(l_acc[r], off);
    l_acc[r] = 1.0f / l_acc[r];
  }
  const long obase = (long)(b * Ss + qt * 128 + wave * 16) * (NH * Dd) + h * Dd;
#pragma unroll
  for (int dt = 0; dt < 8; dt++)
#pragma unroll
    for (int r = 0; r < 4; r++) {
      int row = quad * 4 + r, col = dt * 16 + l16;
      ctx[obase + (long)row * (NH * Dd) + col] = f2bf(o[dt][r] * l_acc[r]);
    }
}

extern "C" void kernel_launch(void* const* d_in, const int* in_sizes, int n_in,
                              void* d_out, int out_size, void* d_ws, size_t ws_size,
                              hipStream_t stream) {
  const float* hidden = (const float*)d_in[0];
  const int* positions = (const int*)d_in[1];
  const float* Wq = (const float*)d_in[2];
  const float* Wk = (const float*)d_in[3];
  const float* Wv = (const float*)d_in[4];
  const float* Wo = (const float*)d_in[5];
  const float* qw = (const float*)d_in[6];
  const float* kw = (const float*)d_in[7];
  float* out = (float*)d_out;

  // 64 MB workspace layout:
  char* ws = (char*)d_ws;
  ushort_t* Xbf = (ushort_t*)(ws);                    // 16 MB (4096x2048 bf16)
  ushort_t* WqkvT = (ushort_t*)(ws + (16l << 20));    // 12 MB (3072x2048 bf16)
  ushort_t* WoT = (ushort_t*)(ws + (28l << 20));      //  8 MB (2048x2048 bf16)
  ushort_t* qkvb = (ushort_t*)(ws + (36l << 20));     // 24 MB (4096x3072 bf16)
  ushort_t* Vt = (ushort_t*)(ws + (60l << 20));       //  4 MB (B,NKV,D,S bf16)
  ushort_t* ctx = Xbf;                                // reuse (dead after GEMM1)

  const long nX = (long)Bb * Ss * HID;
  convert_f32_bf16<<<(unsigned)(nX / 4 / 256), 256, 0, stream>>>(hidden, Xbf, nX);
  transpose_f32_bf16<<<dim3(2048 / 32, 2048 / 32), 256, 0, stream>>>(Wq, WqkvT, 2048, 2048);
  transpose_f32_bf16<<<dim3(512 / 32, 2048 / 32), 256, 0, stream>>>(Wk, WqkvT + (long)2048 * 2048, 2048, 512);
  transpose_f32_bf16<<<dim3(512 / 32, 2048 / 32), 256, 0, stream>>>(Wv, WqkvT + (long)2560 * 2048, 2048, 512);
  transpose_f32_bf16<<<dim3(2048 / 32, 2048 / 32), 256, 0, stream>>>(Wo, WoT, 2048, 2048);

  gemm_bt<ushort_t><<<dim3(3072 / 128, 4096 / 128), 256, 0, stream>>>(Xbf, WqkvT, qkvb, 4096, 3072, 2048);

  rmsnorm_rope<<<(Bb * Ss * 20) / 4, 256, 0, stream>>>(qkvb, positions, qw, kw);
  transpose_v<<<dim3(Ss / 64, Dd / 64, Bb * NKV), 256, 0, stream>>>(qkvb, Vt);

  flash_attn<<<dim3(Ss / 128, NH, Bb), 512, 0, stream>>>(qkvb, Vt, ctx);

  gemm_bt<float><<<dim3(2048 / 128, 4096 / 128), 256, 0, stream>>>(ctx, WoT, out, 4096, 2048, 2048);
}

// Round 5
// 370.446 us; speedup vs baseline: 1.1482x; 1.1482x over previous
//
#include <hip/hip_runtime.h>

typedef unsigned short ushort_t;
typedef __attribute__((ext_vector_type(8))) short short8;
typedef __attribute__((ext_vector_type(4))) float f32x4;

#define Bb 2
#define Ss 2048
#define HID 2048
#define NH 16
#define NKV 4
#define Dd 128
constexpr float EPS_ = 1e-6f;
constexpr float THETA_ = 1000000.0f;
constexpr float SCALE_ = 0.08838834764831845f; // 128^-0.5
constexpr float C2_ = 0.12753785f;             // SCALE * log2(e)

__device__ __forceinline__ ushort_t f2bf(float x) {
  union { float f; unsigned u; } v; v.f = x;
  unsigned r = (v.u + 0x7fffu + ((v.u >> 16) & 1u)) >> 16;
  return (ushort_t)r;
}
__device__ __forceinline__ float bf2f(ushort_t u) {
  union { unsigned u; float f; } v; v.u = ((unsigned)u) << 16;
  return v.f;
}

typedef const __attribute__((address_space(1))) void* gas1_t;
typedef __attribute__((address_space(3))) void* las3_t;
__device__ __forceinline__ void gload_lds16(const void* g, void* l) {
  __builtin_amdgcn_global_load_lds((gas1_t)g, (las3_t)l, 16, 0, 0);
}

__device__ __forceinline__ void store_out(float* p, float v) { *p = v; }
__device__ __forceinline__ void store_out(ushort_t* p, float v) { *p = f2bf(v); }

// ---------------- fp32 -> bf16 straight convert ----------------
__global__ __launch_bounds__(256) void convert_f32_bf16(
    const float* __restrict__ src, ushort_t* __restrict__ dst, long n) {
  long i = ((long)blockIdx.x * 256 + threadIdx.x) * 4;
  if (i + 3 < n) {
    float4 v = *(const float4*)(src + i);
    ushort_t o0 = f2bf(v.x), o1 = f2bf(v.y), o2 = f2bf(v.z), o3 = f2bf(v.w);
    ushort_t* d = dst + i;
    d[0] = o0; d[1] = o1; d[2] = o2; d[3] = o3;
  }
}

// ---------------- fp32 (R x C) -> bf16 transposed (C x R) ----------------
__global__ __launch_bounds__(256) void transpose_f32_bf16(
    const float* __restrict__ src, ushort_t* __restrict__ dst, int R, int C) {
  __shared__ float tile[32][33];
  int c0 = blockIdx.x * 32, r0 = blockIdx.y * 32;
  int tx = threadIdx.x & 31, ty = threadIdx.x >> 5; // ty 0..7
#pragma unroll
  for (int j = 0; j < 4; j++)
    tile[ty + j * 8][tx] = src[(long)(r0 + ty + j * 8) * C + c0 + tx];
  __syncthreads();
#pragma unroll
  for (int j = 0; j < 4; j++)
    dst[(long)(c0 + ty + j * 8) * R + r0 + tx] = f2bf(tile[tx][ty + j * 8]);
}

// ---------------- bf16 GEMM: C[M,N] = A[M,K] * Bt[N,K]^T ----------------
// m97 recipe: 128x128x32 tiles, 4 waves each 64x64, global_load_lds width 16.
template <typename OutT>
__global__ __launch_bounds__(256) void gemm_bt(
    const ushort_t* __restrict__ A, const ushort_t* __restrict__ Bt,
    OutT* __restrict__ C, int M, int N, int K) {
  __shared__ __align__(16) ushort_t As[128 * 32];
  __shared__ __align__(16) ushort_t Bs[128 * 32];
  const int t = threadIdx.x;
  const int wave = t >> 6, lane = t & 63;
  const int wr = wave >> 1, wc = wave & 1;
  const int quad = lane >> 4, l16 = lane & 15;
  const long bm = (long)blockIdx.y * 128, bn = (long)blockIdx.x * 128;

  f32x4 acc[4][4] = {};

  const int srow = t >> 2, schunk = t & 3;
  const ushort_t* aSrc = A + (bm + srow) * (long)K + schunk * 8;
  const ushort_t* bSrc = Bt + (bn + srow) * (long)K + schunk * 8;
  const int ldsOff = srow * 32 + schunk * 8;

  for (int k0 = 0; k0 < K; k0 += 32) {
    __syncthreads();
    gload_lds16(aSrc + k0, &As[ldsOff]);
    gload_lds16(aSrc + (long)64 * K + k0, &As[ldsOff + 64 * 32]);
    gload_lds16(bSrc + k0, &Bs[ldsOff]);
    gload_lds16(bSrc + (long)64 * K + k0, &Bs[ldsOff + 64 * 32]);
    __syncthreads();
    short8 af[4], bf[4];
#pragma unroll
    for (int i = 0; i < 4; i++) {
      af[i] = *(const short8*)&As[(wr * 64 + i * 16 + l16) * 32 + quad * 8];
      bf[i] = *(const short8*)&Bs[(wc * 64 + i * 16 + l16) * 32 + quad * 8];
    }
#pragma unroll
    for (int i = 0; i < 4; i++)
#pragma unroll
      for (int j = 0; j < 4; j++)
        acc[i][j] = __builtin_amdgcn_mfma_f32_16x16x32_bf16(af[i], bf[j], acc[i][j], 0, 0, 0);
  }
#pragma unroll
  for (int i = 0; i < 4; i++)
#pragma unroll
    for (int j = 0; j < 4; j++)
#pragma unroll
      for (int r = 0; r < 4; r++) {
        long rr = bm + wr * 64 + i * 16 + quad * 4 + r;
        long cc = bn + wc * 64 + j * 16 + l16;
        store_out(&C[rr * N + cc], acc[i][j][r]);
      }
}

// ---------------- RMSNorm + RoPE, in place on bf16 qkv ----------------
__global__ __launch_bounds__(256) void rmsnorm_rope(
    ushort_t* __restrict__ qkv, const int* __restrict__ positions,
    const float* __restrict__ qw, const float* __restrict__ kw) {
  int gw = blockIdx.x * 4 + (threadIdx.x >> 6);
  int lane = threadIdx.x & 63;
  int bs = gw / 20, h = gw % 20;
  ushort_t* src = qkv + (long)bs * 3072 + h * 128;
  float x0 = bf2f(src[lane]), x1 = bf2f(src[lane + 64]);
  float ss = x0 * x0 + x1 * x1;
#pragma unroll
  for (int off = 32; off; off >>= 1) ss += __shfl_xor(ss, off);
  float r = rsqrtf(ss * (1.0f / 128.0f) + EPS_);
  const float* w = (h < 16) ? qw : kw;
  x0 = x0 * r * w[lane];
  x1 = x1 * r * w[lane + 64];
  float pos = (float)positions[bs];
  float inv_freq = powf(THETA_, -(float)lane * (1.0f / 64.0f));
  float f = pos * inv_freq;
  float sn, cs;
  sincosf(f, &sn, &cs);
  float o0 = x0 * cs - x1 * sn;
  float o1 = x1 * cs + x0 * sn;
  src[lane] = f2bf(o0);
  src[lane + 64] = f2bf(o1);
}

// ------ V transpose: qkv [B,S,3072] v-columns -> Vt [B,NKV,D,S] ------
__global__ __launch_bounds__(256) void transpose_v(
    const ushort_t* __restrict__ qkv, ushort_t* __restrict__ Vt) {
  __shared__ ushort_t tile[64][65];
  int bh = blockIdx.z; // b*NKV + hk
  int s0 = blockIdx.x * 64, d0 = blockIdx.y * 64;
  int b = bh >> 2, hk = bh & 3;
  int tx = threadIdx.x & 63, ty = threadIdx.x >> 6; // ty 0..3
#pragma unroll
  for (int j = 0; j < 16; j++) {
    int sl = j * 4 + ty;
    tile[sl][tx] = qkv[(long)(b * Ss + s0 + sl) * 3072 + 2560 + hk * 128 + d0 + tx];
  }
  __syncthreads();
  const long vtbase = (long)bh * Dd * Ss;
#pragma unroll
  for (int j = 0; j < 16; j++) {
    int dl = j * 4 + ty;
    Vt[vtbase + (long)(d0 + dl) * Ss + s0 + tx] = tile[tx][dl];
  }
}

// ---------------- flash attention ----------------
// grid (S/128, NH, B); 512 threads = 8 waves; wave w owns Q rows
// [qt*128 + w*16, +16). Double-buffered K/V staging (R1 skeleton, 144us).
// R5 (isolation round, minimal diff from R1): swapped QK^T ONLY.
//   mfma(K,Q) -> sa[nt][r] = S[key = nt*16 + quad*4 + r][q = l16]
//   (swap validity is pinned by R1: identical placement on both operands
//    passing proves the operand k-maps pair symmetrically).
//   - row max: 15 in-lane fmax + 2 shfl_xor (vs R1's 4x 4-deep chains)
//   - l: per-lane partial, single epilogue reduce (vs 16 shfl/iter)
//   - NO defer-max, NO cvt_pk, NO setprio (R3/R4 suspects removed):
//     unconditional online update; P stored with R1's scalar f2bf stores.
//   - P store addressing for transposed layout: key = nt*16+quad*4+r,
//     chunk c = nt*2+(quad>>1), swizzled cl = c^(l16&7), in-chunk
//     (quad&1)*4+r; read back with R1's ((kc*4+quad)^(l16&7)) pattern.
// VGPR must stay <= 64 (R2 lesson: 68 VGPR halves residency 2->1 block/CU).
__global__ __launch_bounds__(512) void flash_attn(
    const ushort_t* __restrict__ qkv, const ushort_t* __restrict__ Vt,
    ushort_t* __restrict__ ctx) {
  __shared__ __align__(16) ushort_t Ks[2][64 * 128];   // [kvrow][d] (16 chunks/row)
  __shared__ __align__(16) ushort_t Vs[2][128 * 64];   // [d][kv]    (8 chunks/row)
  __shared__ __align__(16) ushort_t Ps[8][16 * 64];    // per-wave P [q][key]
  const int qt = blockIdx.x, h = blockIdx.y, b = blockIdx.z;
  const int hk = h >> 2;
  const int t = threadIdx.x, wave = t >> 6, lane = t & 63;
  const int quad = lane >> 4, l16 = lane & 15;

  const ushort_t* qp = qkv + (long)(b * Ss + qt * 128) * 3072 + h * 128;
  const ushort_t* kp = qkv + (long)(b * Ss) * 3072 + 2048 + hk * 128;
  const ushort_t* vp = Vt + ((long)(b * NKV + hk) * Dd) * Ss;

  // staging: issue 4 global_load_lds (2 K-chunks + 2 V-chunks) for tile kt
  auto stage = [&](int kt, int bi) {
    const int k0 = kt * 64;
#pragma unroll
    for (int it = 0; it < 2; it++) {
      int tt = t + it * 512;
      int row = tt >> 4, cl = tt & 15, cg = cl ^ (row & 15);
      gload_lds16(kp + (long)(k0 + row) * 3072 + cg * 8, &Ks[bi][tt * 8]);
    }
#pragma unroll
    for (int it = 0; it < 2; it++) {
      int tt = t + it * 512;
      int row = tt >> 3, cl = tt & 7, cg = cl ^ (row & 7);
      gload_lds16(vp + (long)row * Ss + k0 + cg * 8, &Vs[bi][tt * 8]);
    }
  };

  // prologue: stage tile 0 into buf 0; Q-fragment loads fly alongside
  stage(0, 0);

  // Q fragments straight to registers (B-operand of the swapped QK^T;
  // same per-lane placement as R1 -- only the mfma operand order changed).
  short8 qf[4];
  {
    const ushort_t* qrow = qp + (long)(wave * 16 + l16) * 3072 + quad * 8;
#pragma unroll
    for (int kc = 0; kc < 4; kc++)
      qf[kc] = *(const short8*)(qrow + kc * 32);
  }

  float m_i = -1e30f;   // running max for q = l16 (replicated across quads)
  float l_acc = 0.f;    // per-lane partial denom (q = l16, this quad's keys)
  f32x4 o[8] = {};      // output: q = quad*4+r, d = dt*16+l16

  asm volatile("s_waitcnt vmcnt(0)" ::: "memory");
  __syncthreads();

  int cur = 0;
  for (int kt = 0; kt < Ss / 64; kt++) {
    if (kt + 1 < Ss / 64) stage(kt + 1, cur ^ 1);

    // S^T: sa[nt][r] = S[key = nt*16 + quad*4 + r][q = l16]
    f32x4 sa[4] = {};
#pragma unroll
    for (int kc = 0; kc < 4; kc++) {
#pragma unroll
      for (int nt = 0; nt < 4; nt++) {
        int brow = nt * 16 + l16;
        short8 kfr = *(const short8*)&Ks[cur][brow * 128 + (((kc * 4 + quad) ^ (brow & 15)) * 8)];
        sa[nt] = __builtin_amdgcn_mfma_f32_16x16x32_bf16(kfr, qf[kc], sa[nt], 0, 0, 0);
      }
    }

    // row max: in-lane over this quad's 16 keys, then 2 shfl_xor across quads
    float pmax = sa[0][0];
#pragma unroll
    for (int nt = 0; nt < 4; nt++)
#pragma unroll
      for (int r = 0; r < 4; r++) pmax = fmaxf(pmax, sa[nt][r]);
    float mx = fmaxf(pmax, __shfl_xor(pmax, 16));
    mx = fmaxf(mx, __shfl_xor(mx, 32)); // full row max, replicated all quads

    // online update (unconditional, R1-equivalent arithmetic)
    float mnew = fmaxf(m_i, mx);
    float alpha = __builtin_amdgcn_exp2f((m_i - mnew) * C2_);
    m_i = mnew;
    float mC2 = mnew * C2_;

    // P = exp2(S*C2 - mC2); scalar f2bf stores to Ps (R1's rounding);
    // per-lane row-sum partial.
    float rs = 0.f;
#pragma unroll
    for (int nt = 0; nt < 4; nt++) {
      int cbase = l16 * 64 + ((nt * 2 + (quad >> 1)) ^ (l16 & 7)) * 8 + (quad & 1) * 4;
#pragma unroll
      for (int r = 0; r < 4; r++) {
        float p = __builtin_amdgcn_exp2f(__builtin_fmaf(sa[nt][r], C2_, -mC2));
        rs += p;
        union { float f; unsigned u; } pv; pv.f = p;
        Ps[wave][cbase + r] = (ushort_t)((pv.u + 0x8000u) >> 16);
      }
    }
    l_acc = l_acc * alpha + rs;

    // rescale O (alpha for q=quad*4+r via broadcast from quad-0 lanes);
    // independent VALU work while the P stores drain
    float ar0 = __shfl(alpha, quad * 4 + 0);
    float ar1 = __shfl(alpha, quad * 4 + 1);
    float ar2 = __shfl(alpha, quad * 4 + 2);
    float ar3 = __shfl(alpha, quad * 4 + 3);
#pragma unroll
    for (int dt = 0; dt < 8; dt++) {
      o[dt][0] *= ar0; o[dt][1] *= ar1; o[dt][2] *= ar2; o[dt][3] *= ar3;
    }
    asm volatile("s_waitcnt lgkmcnt(0)" ::: "memory");

    // O += P V  (A-frag: P[q=l16][keys kc*32+quad*8..+7], R1 read pattern)
#pragma unroll
    for (int kc = 0; kc < 2; kc++) {
      int arow = l16;
      short8 af = *(const short8*)&Ps[wave][arow * 64 + (((kc * 4 + quad) ^ (arow & 7)) * 8)];
#pragma unroll
      for (int dt = 0; dt < 8; dt++) {
        int brow = dt * 16 + l16;
        short8 bfr = *(const short8*)&Vs[cur][brow * 64 + (((kc * 4 + quad) ^ (brow & 7)) * 8)];
        o[dt] = __builtin_amdgcn_mfma_f32_16x16x32_bf16(af, bfr, o[dt], 0, 0, 0);
      }
    }

    // publish next tile (vmcnt drain) + protect this buffer (barrier)
    asm volatile("s_waitcnt vmcnt(0)" ::: "memory");
    __syncthreads();
    cur ^= 1;
  }

  // epilogue: reduce l across quads (disjoint keys, same alpha history),
  // broadcast 1/l into o's row space, write ctx [B*S, NH*D]
  float lt = l_acc + __shfl_xor(l_acc, 16);
  lt += __shfl_xor(lt, 32);
  float linv = 1.0f / lt;
  float lr0 = __shfl(linv, quad * 4 + 0);
  float lr1 = __shfl(linv, quad * 4 + 1);
  float lr2 = __shfl(linv, quad * 4 + 2);
  float lr3 = __shfl(linv, quad * 4 + 3);
  const long obase = (long)(b * Ss + qt * 128 + wave * 16) * (NH * Dd) + h * Dd;
#pragma unroll
  for (int dt = 0; dt < 8; dt++) {
    int col = dt * 16 + l16;
    ctx[obase + (long)(quad * 4 + 0) * (NH * Dd) + col] = f2bf(o[dt][0] * lr0);
    ctx[obase + (long)(quad * 4 + 1) * (NH * Dd) + col] = f2bf(o[dt][1] * lr1);
    ctx[obase + (long)(quad * 4 + 2) * (NH * Dd) + col] = f2bf(o[dt][2] * lr2);
    ctx[obase + (long)(quad * 4 + 3) * (NH * Dd) + col] = f2bf(o[dt][3] * lr3);
  }
}

extern "C" void kernel_launch(void* const* d_in, const int* in_sizes, int n_in,
                              void* d_out, int out_size, void* d_ws, size_t ws_size,
                              hipStream_t stream) {
  const float* hidden = (const float*)d_in[0];
  const int* positions = (const int*)d_in[1];
  const float* Wq = (const float*)d_in[2];
  const float* Wk = (const float*)d_in[3];
  const float* Wv = (const float*)d_in[4];
  const float* Wo = (const float*)d_in[5];
  const float* qw = (const float*)d_in[6];
  const float* kw = (const float*)d_in[7];
  float* out = (float*)d_out;

  // 64 MB workspace layout:
  char* ws = (char*)d_ws;
  ushort_t* Xbf = (ushort_t*)(ws);                    // 16 MB (4096x2048 bf16)
  ushort_t* WqkvT = (ushort_t*)(ws + (16l << 20));    // 12 MB (3072x2048 bf16)
  ushort_t* WoT = (ushort_t*)(ws + (28l << 20));      //  8 MB (2048x2048 bf16)
  ushort_t* qkvb = (ushort_t*)(ws + (36l << 20));     // 24 MB (4096x3072 bf16)
  ushort_t* Vt = (ushort_t*)(ws + (60l << 20));       //  4 MB (B,NKV,D,S bf16)
  ushort_t* ctx = Xbf;                                // reuse (dead after GEMM1)

  const long nX = (long)Bb * Ss * HID;
  convert_f32_bf16<<<(unsigned)(nX / 4 / 256), 256, 0, stream>>>(hidden, Xbf, nX);
  transpose_f32_bf16<<<dim3(2048 / 32, 2048 / 32), 256, 0, stream>>>(Wq, WqkvT, 2048, 2048);
  transpose_f32_bf16<<<dim3(512 / 32, 2048 / 32), 256, 0, stream>>>(Wk, WqkvT + (long)2048 * 2048, 2048, 512);
  transpose_f32_bf16<<<dim3(512 / 32, 2048 / 32), 256, 0, stream>>>(Wv, WqkvT + (long)2560 * 2048, 2048, 512);
  transpose_f32_bf16<<<dim3(2048 / 32, 2048 / 32), 256, 0, stream>>>(Wo, WoT, 2048, 2048);

  gemm_bt<ushort_t><<<dim3(3072 / 128, 4096 / 128), 256, 0, stream>>>(Xbf, WqkvT, qkvb, 4096, 3072, 2048);

  rmsnorm_rope<<<(Bb * Ss * 20) / 4, 256, 0, stream>>>(qkvb, positions, qw, kw);
  transpose_v<<<dim3(Ss / 64, Dd / 64, Bb * NKV), 256, 0, stream>>>(qkvb, Vt);

  flash_attn<<<dim3(Ss / 128, NH, Bb), 512, 0, stream>>>(qkvb, Vt, ctx);

  gemm_bt<float><<<dim3(2048 / 128, 4096 / 128), 256, 0, stream>>>(ctx, WoT, out, 4096, 2048, 2048);
}

// Round 6
// 360.763 us; speedup vs baseline: 1.1791x; 1.0268x over previous
//
#include <hip/hip_runtime.h>

typedef unsigned short ushort_t;
typedef __attribute__((ext_vector_type(8))) short short8;
typedef __attribute__((ext_vector_type(4))) float f32x4;

#define Bb 2
#define Ss 2048
#define HID 2048
#define NH 16
#define NKV 4
#define Dd 128
constexpr float EPS_ = 1e-6f;
constexpr float THETA_ = 1000000.0f;
constexpr float SCALE_ = 0.08838834764831845f; // 128^-0.5
constexpr float C2_ = 0.12753785f;             // SCALE * log2(e)
constexpr float THR_RAW_ = 23.5f;              // 3 / C2_: defer-max threshold (P <= 8)

__device__ __forceinline__ ushort_t f2bf(float x) {
  union { float f; unsigned u; } v; v.f = x;
  unsigned r = (v.u + 0x7fffu + ((v.u >> 16) & 1u)) >> 16;
  return (ushort_t)r;
}
__device__ __forceinline__ float bf2f(ushort_t u) {
  union { unsigned u; float f; } v; v.u = ((unsigned)u) << 16;
  return v.f;
}

typedef const __attribute__((address_space(1))) void* gas1_t;
typedef __attribute__((address_space(3))) void* las3_t;
__device__ __forceinline__ void gload_lds16(const void* g, void* l) {
  __builtin_amdgcn_global_load_lds((gas1_t)g, (las3_t)l, 16, 0, 0);
}

__device__ __forceinline__ void store_out(float* p, float v) { *p = v; }
__device__ __forceinline__ void store_out(ushort_t* p, float v) { *p = f2bf(v); }

// ---------------- fp32 -> bf16 straight convert ----------------
__global__ __launch_bounds__(256) void convert_f32_bf16(
    const float* __restrict__ src, ushort_t* __restrict__ dst, long n) {
  long i = ((long)blockIdx.x * 256 + threadIdx.x) * 4;
  if (i + 3 < n) {
    float4 v = *(const float4*)(src + i);
    ushort_t o0 = f2bf(v.x), o1 = f2bf(v.y), o2 = f2bf(v.z), o3 = f2bf(v.w);
    ushort_t* d = dst + i;
    d[0] = o0; d[1] = o1; d[2] = o2; d[3] = o3;
  }
}

// ---------------- fp32 (R x C) -> bf16 transposed (C x R) ----------------
__global__ __launch_bounds__(256) void transpose_f32_bf16(
    const float* __restrict__ src, ushort_t* __restrict__ dst, int R, int C) {
  __shared__ float tile[32][33];
  int c0 = blockIdx.x * 32, r0 = blockIdx.y * 32;
  int tx = threadIdx.x & 31, ty = threadIdx.x >> 5; // ty 0..7
#pragma unroll
  for (int j = 0; j < 4; j++)
    tile[ty + j * 8][tx] = src[(long)(r0 + ty + j * 8) * C + c0 + tx];
  __syncthreads();
#pragma unroll
  for (int j = 0; j < 4; j++)
    dst[(long)(c0 + ty + j * 8) * R + r0 + tx] = f2bf(tile[tx][ty + j * 8]);
}

// ---------------- bf16 GEMM: C[M,N] = A[M,K] * Bt[N,K]^T ----------------
// m97 recipe: 128x128x32 tiles, 4 waves each 64x64, global_load_lds width 16.
// R6: bijective XCD-aware tile swizzle (T1) -- consecutive tiles within one
// XCD share the A-panel -> L2-local A reads. nwg%8==0 for both launches.
template <typename OutT>
__global__ __launch_bounds__(256) void gemm_bt(
    const ushort_t* __restrict__ A, const ushort_t* __restrict__ Bt,
    OutT* __restrict__ C, int M, int N, int K) {
  __shared__ __align__(16) ushort_t As[128 * 32];
  __shared__ __align__(16) ushort_t Bs[128 * 32];
  const int t = threadIdx.x;
  const int wave = t >> 6, lane = t & 63;
  const int wr = wave >> 1, wc = wave & 1;
  const int quad = lane >> 4, l16 = lane & 15;

  unsigned gx = gridDim.x;
  unsigned nwg = gx * gridDim.y;
  unsigned lin = blockIdx.y * gx + blockIdx.x;
  if ((nwg & 7u) == 0u) {
    unsigned cpx = nwg >> 3;
    lin = (lin & 7u) * cpx + (lin >> 3);
  }
  const long bm = (long)(lin / gx) * 128;
  const long bn = (long)(lin % gx) * 128;

  f32x4 acc[4][4] = {};

  const int srow = t >> 2, schunk = t & 3;
  const ushort_t* aSrc = A + (bm + srow) * (long)K + schunk * 8;
  const ushort_t* bSrc = Bt + (bn + srow) * (long)K + schunk * 8;
  const int ldsOff = srow * 32 + schunk * 8;

  for (int k0 = 0; k0 < K; k0 += 32) {
    __syncthreads();
    gload_lds16(aSrc + k0, &As[ldsOff]);
    gload_lds16(aSrc + (long)64 * K + k0, &As[ldsOff + 64 * 32]);
    gload_lds16(bSrc + k0, &Bs[ldsOff]);
    gload_lds16(bSrc + (long)64 * K + k0, &Bs[ldsOff + 64 * 32]);
    __syncthreads();
    short8 af[4], bf[4];
#pragma unroll
    for (int i = 0; i < 4; i++) {
      af[i] = *(const short8*)&As[(wr * 64 + i * 16 + l16) * 32 + quad * 8];
      bf[i] = *(const short8*)&Bs[(wc * 64 + i * 16 + l16) * 32 + quad * 8];
    }
#pragma unroll
    for (int i = 0; i < 4; i++)
#pragma unroll
      for (int j = 0; j < 4; j++)
        acc[i][j] = __builtin_amdgcn_mfma_f32_16x16x32_bf16(af[i], bf[j], acc[i][j], 0, 0, 0);
  }
#pragma unroll
  for (int i = 0; i < 4; i++)
#pragma unroll
    for (int j = 0; j < 4; j++)
#pragma unroll
      for (int r = 0; r < 4; r++) {
        long rr = bm + wr * 64 + i * 16 + quad * 4 + r;
        long cc = bn + wc * 64 + j * 16 + l16;
        store_out(&C[rr * N + cc], acc[i][j][r]);
      }
}

// ---------------- RMSNorm + RoPE, in place on bf16 qkv ----------------
__global__ __launch_bounds__(256) void rmsnorm_rope(
    ushort_t* __restrict__ qkv, const int* __restrict__ positions,
    const float* __restrict__ qw, const float* __restrict__ kw) {
  int gw = blockIdx.x * 4 + (threadIdx.x >> 6);
  int lane = threadIdx.x & 63;
  int bs = gw / 20, h = gw % 20;
  ushort_t* src = qkv + (long)bs * 3072 + h * 128;
  float x0 = bf2f(src[lane]), x1 = bf2f(src[lane + 64]);
  float ss = x0 * x0 + x1 * x1;
#pragma unroll
  for (int off = 32; off; off >>= 1) ss += __shfl_xor(ss, off);
  float r = rsqrtf(ss * (1.0f / 128.0f) + EPS_);
  const float* w = (h < 16) ? qw : kw;
  x0 = x0 * r * w[lane];
  x1 = x1 * r * w[lane + 64];
  float pos = (float)positions[bs];
  float inv_freq = powf(THETA_, -(float)lane * (1.0f / 64.0f));
  float f = pos * inv_freq;
  float sn, cs;
  sincosf(f, &sn, &cs);
  float o0 = x0 * cs - x1 * sn;
  float o1 = x1 * cs + x0 * sn;
  src[lane] = f2bf(o0);
  src[lane + 64] = f2bf(o1);
}

// ------ V transpose: qkv [B,S,3072] v-columns -> Vt [B,NKV,D,S] ------
__global__ __launch_bounds__(256) void transpose_v(
    const ushort_t* __restrict__ qkv, ushort_t* __restrict__ Vt) {
  __shared__ ushort_t tile[64][65];
  int bh = blockIdx.z; // b*NKV + hk
  int s0 = blockIdx.x * 64, d0 = blockIdx.y * 64;
  int b = bh >> 2, hk = bh & 3;
  int tx = threadIdx.x & 63, ty = threadIdx.x >> 6; // ty 0..3
#pragma unroll
  for (int j = 0; j < 16; j++) {
    int sl = j * 4 + ty;
    tile[sl][tx] = qkv[(long)(b * Ss + s0 + sl) * 3072 + 2560 + hk * 128 + d0 + tx];
  }
  __syncthreads();
  const long vtbase = (long)bh * Dd * Ss;
#pragma unroll
  for (int j = 0; j < 16; j++) {
    int dl = j * 4 + ty;
    Vt[vtbase + (long)(d0 + dl) * Ss + s0 + tx] = tile[tx][dl];
  }
}

// ---------------- flash attention ----------------
// grid (S/128, NH, B); 512 threads = 8 waves; wave w owns Q rows
// [qt*128 + w*16, +16). Double-buffered K/V staging; swapped QK^T
// (R5 verified, 98us): sa[nt][r] = S[key = nt*16+quad*4+r][q = l16].
// R6 adds (on the R5 skeleton):
//  - defer-max (T13): wave-uniform __any vote; common path skips the
//    m-update, the row-max cross-quad reduce, and the 32-mul O-rescale.
//    O-rescale placed AFTER the P-store loop (sa dead) so ar0-3 and sa
//    are never co-live -> protects the 64-VGPR budget (R2 cliff lesson).
//  - s_setprio(1) around both MFMA clusters (T5).
// Verified-correct pieces kept bit-identical: P-store swizzle (R5),
// staging (R1), epilogue (R5).
__global__ __launch_bounds__(512) void flash_attn(
    const ushort_t* __restrict__ qkv, const ushort_t* __restrict__ Vt,
    ushort_t* __restrict__ ctx) {
  __shared__ __align__(16) ushort_t Ks[2][64 * 128];   // [kvrow][d] (16 chunks/row)
  __shared__ __align__(16) ushort_t Vs[2][128 * 64];   // [d][kv]    (8 chunks/row)
  __shared__ __align__(16) ushort_t Ps[8][16 * 64];    // per-wave P [q][key]
  const int qt = blockIdx.x, h = blockIdx.y, b = blockIdx.z;
  const int hk = h >> 2;
  const int t = threadIdx.x, wave = t >> 6, lane = t & 63;
  const int quad = lane >> 4, l16 = lane & 15;

  const ushort_t* qp = qkv + (long)(b * Ss + qt * 128) * 3072 + h * 128;
  const ushort_t* kp = qkv + (long)(b * Ss) * 3072 + 2048 + hk * 128;
  const ushort_t* vp = Vt + ((long)(b * NKV + hk) * Dd) * Ss;

  // staging: issue 4 global_load_lds (2 K-chunks + 2 V-chunks) for tile kt
  auto stage = [&](int kt, int bi) {
    const int k0 = kt * 64;
#pragma unroll
    for (int it = 0; it < 2; it++) {
      int tt = t + it * 512;
      int row = tt >> 4, cl = tt & 15, cg = cl ^ (row & 15);
      gload_lds16(kp + (long)(k0 + row) * 3072 + cg * 8, &Ks[bi][tt * 8]);
    }
#pragma unroll
    for (int it = 0; it < 2; it++) {
      int tt = t + it * 512;
      int row = tt >> 3, cl = tt & 7, cg = cl ^ (row & 7);
      gload_lds16(vp + (long)row * Ss + k0 + cg * 8, &Vs[bi][tt * 8]);
    }
  };

  // prologue: stage tile 0 into buf 0; Q-fragment loads fly alongside
  stage(0, 0);

  // Q fragments straight to registers (B-operand of the swapped QK^T).
  short8 qf[4];
  {
    const ushort_t* qrow = qp + (long)(wave * 16 + l16) * 3072 + quad * 8;
#pragma unroll
    for (int kc = 0; kc < 4; kc++)
      qf[kc] = *(const short8*)(qrow + kc * 32);
  }

  float m_i = -1e30f;   // running max for q = l16 (replicated across quads)
  float l_acc = 0.f;    // per-lane partial denom (q = l16, this quad's keys)
  f32x4 o[8] = {};      // output: q = quad*4+r, d = dt*16+l16

  asm volatile("s_waitcnt vmcnt(0)" ::: "memory");
  __syncthreads();

  int cur = 0;
  for (int kt = 0; kt < Ss / 64; kt++) {
    if (kt + 1 < Ss / 64) stage(kt + 1, cur ^ 1);

    // S^T: sa[nt][r] = S[key = nt*16 + quad*4 + r][q = l16]
    f32x4 sa[4] = {};
    __builtin_amdgcn_s_setprio(1);
#pragma unroll
    for (int kc = 0; kc < 4; kc++) {
#pragma unroll
      for (int nt = 0; nt < 4; nt++) {
        int brow = nt * 16 + l16;
        short8 kfr = *(const short8*)&Ks[cur][brow * 128 + (((kc * 4 + quad) ^ (brow & 15)) * 8)];
        sa[nt] = __builtin_amdgcn_mfma_f32_16x16x32_bf16(kfr, qf[kc], sa[nt], 0, 0, 0);
      }
    }
    __builtin_amdgcn_s_setprio(0);

    // per-quad partial row max (in-lane, 16 values for this lane's q-row)
    float pmax = sa[0][0];
#pragma unroll
    for (int nt = 0; nt < 4; nt++)
#pragma unroll
      for (int r = 0; r < 4; r++) pmax = fmaxf(pmax, sa[nt][r]);

    // defer-max: wave-uniform vote. Rare path: full row max + m update +
    // l rescale now; O rescale deferred to after the P loop (sa dead).
    bool upd = __any(pmax > m_i + THR_RAW_);
    float alpha = 1.0f;
    if (upd) {
      float mx = fmaxf(pmax, __shfl_xor(pmax, 16));
      mx = fmaxf(mx, __shfl_xor(mx, 32));        // true row max, all quads
      float mnew = fmaxf(m_i, mx);
      alpha = __builtin_amdgcn_exp2f((m_i - mnew) * C2_);
      m_i = mnew;
      l_acc *= alpha;
    }

    // P = exp2(S*C2 - mC2); scalar f2bf stores to Ps (R5-verified swizzle);
    // per-lane row-sum partial.
    float mC2 = m_i * C2_;
    float rs = 0.f;
#pragma unroll
    for (int nt = 0; nt < 4; nt++) {
      int cbase = l16 * 64 + ((nt * 2 + (quad >> 1)) ^ (l16 & 7)) * 8 + (quad & 1) * 4;
#pragma unroll
      for (int r = 0; r < 4; r++) {
        float p = __builtin_amdgcn_exp2f(__builtin_fmaf(sa[nt][r], C2_, -mC2));
        rs += p;
        union { float f; unsigned u; } pv; pv.f = p;
        Ps[wave][cbase + r] = (ushort_t)((pv.u + 0x8000u) >> 16);
      }
    }
    l_acc += rs;

    // deferred O-rescale (rare); alpha for q=quad*4+r via lane broadcast
    if (upd) {
      float ar0 = __shfl(alpha, quad * 4 + 0);
      float ar1 = __shfl(alpha, quad * 4 + 1);
      float ar2 = __shfl(alpha, quad * 4 + 2);
      float ar3 = __shfl(alpha, quad * 4 + 3);
#pragma unroll
      for (int dt = 0; dt < 8; dt++) {
        o[dt][0] *= ar0; o[dt][1] *= ar1; o[dt][2] *= ar2; o[dt][3] *= ar3;
      }
    }
    asm volatile("s_waitcnt lgkmcnt(0)" ::: "memory");

    // O += P V  (A-frag: P[q=l16][keys kc*32+quad*8..+7], R1 read pattern)
    __builtin_amdgcn_s_setprio(1);
#pragma unroll
    for (int kc = 0; kc < 2; kc++) {
      int arow = l16;
      short8 af = *(const short8*)&Ps[wave][arow * 64 + (((kc * 4 + quad) ^ (arow & 7)) * 8)];
#pragma unroll
      for (int dt = 0; dt < 8; dt++) {
        int brow = dt * 16 + l16;
        short8 bfr = *(const short8*)&Vs[cur][brow * 64 + (((kc * 4 + quad) ^ (brow & 7)) * 8)];
        o[dt] = __builtin_amdgcn_mfma_f32_16x16x32_bf16(af, bfr, o[dt], 0, 0, 0);
      }
    }
    __builtin_amdgcn_s_setprio(0);

    // publish next tile (vmcnt drain) + protect this buffer (barrier)
    asm volatile("s_waitcnt vmcnt(0)" ::: "memory");
    __syncthreads();
    cur ^= 1;
  }

  // epilogue: reduce l across quads (disjoint keys, same alpha history),
  // broadcast 1/l into o's row space, write ctx [B*S, NH*D]
  float lt = l_acc + __shfl_xor(l_acc, 16);
  lt += __shfl_xor(lt, 32);
  float linv = 1.0f / lt;
  float lr0 = __shfl(linv, quad * 4 + 0);
  float lr1 = __shfl(linv, quad * 4 + 1);
  float lr2 = __shfl(linv, quad * 4 + 2);
  float lr3 = __shfl(linv, quad * 4 + 3);
  const long obase = (long)(b * Ss + qt * 128 + wave * 16) * (NH * Dd) + h * Dd;
#pragma unroll
  for (int dt = 0; dt < 8; dt++) {
    int col = dt * 16 + l16;
    ctx[obase + (long)(quad * 4 + 0) * (NH * Dd) + col] = f2bf(o[dt][0] * lr0);
    ctx[obase + (long)(quad * 4 + 1) * (NH * Dd) + col] = f2bf(o[dt][1] * lr1);
    ctx[obase + (long)(quad * 4 + 2) * (NH * Dd) + col] = f2bf(o[dt][2] * lr2);
    ctx[obase + (long)(quad * 4 + 3) * (NH * Dd) + col] = f2bf(o[dt][3] * lr3);
  }
}

extern "C" void kernel_launch(void* const* d_in, const int* in_sizes, int n_in,
                              void* d_out, int out_size, void* d_ws, size_t ws_size,
                              hipStream_t stream) {
  const float* hidden = (const float*)d_in[0];
  const int* positions = (const int*)d_in[1];
  const float* Wq = (const float*)d_in[2];
  const float* Wk = (const float*)d_in[3];
  const float* Wv = (const float*)d_in[4];
  const float* Wo = (const float*)d_in[5];
  const float* qw = (const float*)d_in[6];
  const float* kw = (const float*)d_in[7];
  float* out = (float*)d_out;

  // 64 MB workspace layout:
  char* ws = (char*)d_ws;
  ushort_t* Xbf = (ushort_t*)(ws);                    // 16 MB (4096x2048 bf16)
  ushort_t* WqkvT = (ushort_t*)(ws + (16l << 20));    // 12 MB (3072x2048 bf16)
  ushort_t* WoT = (ushort_t*)(ws + (28l << 20));      //  8 MB (2048x2048 bf16)
  ushort_t* qkvb = (ushort_t*)(ws + (36l << 20));     // 24 MB (4096x3072 bf16)
  ushort_t* Vt = (ushort_t*)(ws + (60l << 20));       //  4 MB (B,NKV,D,S bf16)
  ushort_t* ctx = Xbf;                                // reuse (dead after GEMM1)

  const long nX = (long)Bb * Ss * HID;
  convert_f32_bf16<<<(unsigned)(nX / 4 / 256), 256, 0, stream>>>(hidden, Xbf, nX);
  transpose_f32_bf16<<<dim3(2048 / 32, 2048 / 32), 256, 0, stream>>>(Wq, WqkvT, 2048, 2048);
  transpose_f32_bf16<<<dim3(512 / 32, 2048 / 32), 256, 0, stream>>>(Wk, WqkvT + (long)2048 * 2048, 2048, 512);
  transpose_f32_bf16<<<dim3(512 / 32, 2048 / 32), 256, 0, stream>>>(Wv, WqkvT + (long)2560 * 2048, 2048, 512);
  transpose_f32_bf16<<<dim3(2048 / 32, 2048 / 32), 256, 0, stream>>>(Wo, WoT, 2048, 2048);

  gemm_bt<ushort_t><<<dim3(3072 / 128, 4096 / 128), 256, 0, stream>>>(Xbf, WqkvT, qkvb, 4096, 3072, 2048);

  rmsnorm_rope<<<(Bb * Ss * 20) / 4, 256, 0, stream>>>(qkvb, positions, qw, kw);
  transpose_v<<<dim3(Ss / 64, Dd / 64, Bb * NKV), 256, 0, stream>>>(qkvb, Vt);

  flash_attn<<<dim3(Ss / 128, NH, Bb), 512, 0, stream>>>(qkvb, Vt, ctx);

  gemm_bt<float><<<dim3(2048 / 128, 4096 / 128), 256, 0, stream>>>(ctx, WoT, out, 4096, 2048, 2048);
}

// Round 7
// 349.877 us; speedup vs baseline: 1.2157x; 1.0311x over previous
//
#include <hip/hip_runtime.h>

typedef unsigned short ushort_t;
typedef __attribute__((ext_vector_type(8))) short short8;
typedef __attribute__((ext_vector_type(4))) float f32x4;

#define Bb 2
#define Ss 2048
#define HID 2048
#define NH 16
#define NKV 4
#define Dd 128
constexpr float EPS_ = 1e-6f;
constexpr float THETA_ = 1000000.0f;
constexpr float SCALE_ = 0.08838834764831845f; // 128^-0.5
constexpr float C2_ = 0.12753785f;             // SCALE * log2(e)
constexpr float THR_RAW_ = 23.5f;              // 3 / C2_: defer-max threshold (P <= 8)

__device__ __forceinline__ ushort_t f2bf(float x) {
  union { float f; unsigned u; } v; v.f = x;
  unsigned r = (v.u + 0x7fffu + ((v.u >> 16) & 1u)) >> 16;
  return (ushort_t)r;
}
__device__ __forceinline__ float bf2f(ushort_t u) {
  union { unsigned u; float f; } v; v.u = ((unsigned)u) << 16;
  return v.f;
}

typedef const __attribute__((address_space(1))) void* gas1_t;
typedef __attribute__((address_space(3))) void* las3_t;
__device__ __forceinline__ void gload_lds16(const void* g, void* l) {
  __builtin_amdgcn_global_load_lds((gas1_t)g, (las3_t)l, 16, 0, 0);
}

__device__ __forceinline__ void store_out(float* p, float v) { *p = v; }
__device__ __forceinline__ void store_out(ushort_t* p, float v) { *p = f2bf(v); }

// ---------------- fp32 -> bf16 straight convert ----------------
__global__ __launch_bounds__(256) void convert_f32_bf16(
    const float* __restrict__ src, ushort_t* __restrict__ dst, long n) {
  long i = ((long)blockIdx.x * 256 + threadIdx.x) * 4;
  if (i + 3 < n) {
    float4 v = *(const float4*)(src + i);
    ushort_t o0 = f2bf(v.x), o1 = f2bf(v.y), o2 = f2bf(v.z), o3 = f2bf(v.w);
    ushort_t* d = dst + i;
    d[0] = o0; d[1] = o1; d[2] = o2; d[3] = o3;
  }
}

// ---------------- fp32 (R x C) -> bf16 transposed (C x R) ----------------
__global__ __launch_bounds__(256) void transpose_f32_bf16(
    const float* __restrict__ src, ushort_t* __restrict__ dst, int R, int C) {
  __shared__ float tile[32][33];
  int c0 = blockIdx.x * 32, r0 = blockIdx.y * 32;
  int tx = threadIdx.x & 31, ty = threadIdx.x >> 5; // ty 0..7
#pragma unroll
  for (int j = 0; j < 4; j++)
    tile[ty + j * 8][tx] = src[(long)(r0 + ty + j * 8) * C + c0 + tx];
  __syncthreads();
#pragma unroll
  for (int j = 0; j < 4; j++)
    dst[(long)(c0 + ty + j * 8) * R + r0 + tx] = f2bf(tile[tx][ty + j * 8]);
}

// ---------------- bf16 GEMM: C[M,N] = A[M,K] * Bt[N,K]^T ----------------
// m97 recipe: 128x128x32 tiles, 4 waves each 64x64, global_load_lds width 16.
// Kept for GEMM2 (2048 cols -> 256^2 tile would leave half the CUs idle).
template <typename OutT>
__global__ __launch_bounds__(256) void gemm_bt(
    const ushort_t* __restrict__ A, const ushort_t* __restrict__ Bt,
    OutT* __restrict__ C, int M, int N, int K) {
  __shared__ __align__(16) ushort_t As[128 * 32];
  __shared__ __align__(16) ushort_t Bs[128 * 32];
  const int t = threadIdx.x;
  const int wave = t >> 6, lane = t & 63;
  const int wr = wave >> 1, wc = wave & 1;
  const int quad = lane >> 4, l16 = lane & 15;

  unsigned gx = gridDim.x;
  unsigned nwg = gx * gridDim.y;
  unsigned lin = blockIdx.y * gx + blockIdx.x;
  if ((nwg & 7u) == 0u) {
    unsigned cpx = nwg >> 3;
    lin = (lin & 7u) * cpx + (lin >> 3);
  }
  const long bm = (long)(lin / gx) * 128;
  const long bn = (long)(lin % gx) * 128;

  f32x4 acc[4][4] = {};

  const int srow = t >> 2, schunk = t & 3;
  const ushort_t* aSrc = A + (bm + srow) * (long)K + schunk * 8;
  const ushort_t* bSrc = Bt + (bn + srow) * (long)K + schunk * 8;
  const int ldsOff = srow * 32 + schunk * 8;

  for (int k0 = 0; k0 < K; k0 += 32) {
    __syncthreads();
    gload_lds16(aSrc + k0, &As[ldsOff]);
    gload_lds16(aSrc + (long)64 * K + k0, &As[ldsOff + 64 * 32]);
    gload_lds16(bSrc + k0, &Bs[ldsOff]);
    gload_lds16(bSrc + (long)64 * K + k0, &Bs[ldsOff + 64 * 32]);
    __syncthreads();
    short8 af[4], bf[4];
#pragma unroll
    for (int i = 0; i < 4; i++) {
      af[i] = *(const short8*)&As[(wr * 64 + i * 16 + l16) * 32 + quad * 8];
      bf[i] = *(const short8*)&Bs[(wc * 64 + i * 16 + l16) * 32 + quad * 8];
    }
#pragma unroll
    for (int i = 0; i < 4; i++)
#pragma unroll
      for (int j = 0; j < 4; j++)
        acc[i][j] = __builtin_amdgcn_mfma_f32_16x16x32_bf16(af[i], bf[j], acc[i][j], 0, 0, 0);
  }
#pragma unroll
  for (int i = 0; i < 4; i++)
#pragma unroll
    for (int j = 0; j < 4; j++)
#pragma unroll
      for (int r = 0; r < 4; r++) {
        long rr = bm + wr * 64 + i * 16 + quad * 4 + r;
        long cc = bn + wc * 64 + j * 16 + l16;
        store_out(&C[rr * N + cc], acc[i][j][r]);
      }
}

// ---------------- 256x256 8-phase bf16 GEMM (T3+T4+T5) ----------------
// 8 waves (2M x 4N), BK=64, LDS 128KB (2 dbuf x [256][64] for A and B).
// Per K-tile: 4 phases by (i-half, j-half) quadrant, 16 MFMA each.
// Staging: one half-tile unit (2 gload_lds/thread) per phase, into a slice
// whose last LDS read finished >=1 barrier ago (dead-slice ledger):
//   p0: (t+1, A-ih1)->buf^1   p1: (t+1, B-jh1)->buf^1
//   p2: (t+2, A-ih0)->buf     p3: (t+2, B-jh0)->buf
// vmcnt(4) ONCE per tile (at p3; 2 units x 2 loads newer than tile t+1),
// never 0 in steady state. Raw s_barrier + sched_barrier(0) so the
// compiler cannot inject the vmcnt(0) barrier-drain that caps m97.
// Swizzle: linear gload_lds dest + inverse-swz global source (cg=cl^(row&7))
// + swz on read (chunk=(kk*4+quad)^(l16&7)) -- session-verified family.
template <typename OutT>
__global__ __launch_bounds__(512) void gemm256_bt(
    const ushort_t* __restrict__ A, const ushort_t* __restrict__ Bt,
    OutT* __restrict__ C, int M, int N, int K) {
  __shared__ __align__(16) ushort_t As[2][256 * 64];
  __shared__ __align__(16) ushort_t Bs[2][256 * 64];
  const int t = threadIdx.x;
  const int wave = t >> 6, lane = t & 63;
  const int wm = wave >> 2, wn = wave & 3;
  const int quad = lane >> 4, l16 = lane & 15;

  unsigned gx = gridDim.x;
  unsigned nwg = gx * gridDim.y;
  unsigned lin = blockIdx.y * gx + blockIdx.x;
  if ((nwg & 7u) == 0u) {
    unsigned cpx = nwg >> 3;
    lin = (lin & 7u) * cpx + (lin >> 3);
  }
  const long bm = (long)(lin / gx) * 256;
  const long bn = (long)(lin % gx) * 256;

  // stage one A half (ih: rows with bit6==ih) of K-tile kt into buf bi
  auto stageA = [&](int kt, int ih, int bi) {
    const int k0 = kt * 64;
#pragma unroll
    for (int it = 0; it < 2; it++) {
      int ci = t + it * 512;
      int lr = ci >> 3, cl = ci & 7;
      int row = ((lr & 64) << 1) | (ih << 6) | (lr & 63);
      int cg = cl ^ (row & 7);
      gload_lds16(A + (bm + row) * (long)K + k0 + cg * 8, &As[bi][row * 64 + cl * 8]);
    }
  };
  // stage one B half (jh: rows with bit5==jh) of K-tile kt into buf bi
  auto stageB = [&](int kt, int jh, int bi) {
    const int k0 = kt * 64;
#pragma unroll
    for (int it = 0; it < 2; it++) {
      int ci = t + it * 512;
      int lr = ci >> 3, cl = ci & 7;
      int row = ((lr & 96) << 1) | (jh << 5) | (lr & 31);
      int cg = cl ^ (row & 7);
      gload_lds16(Bt + (bn + row) * (long)K + k0 + cg * 8, &Bs[bi][row * 64 + cl * 8]);
    }
  };

  f32x4 acc[8][4] = {};
  short8 af[2][4], bf0[2][2], bf1[2][2];

  const int nt = K >> 6;
  // prologue: tile 0 fully + tile 1's (A-ih0, B-jh0); wait tile 0 (4 newer)
  stageA(0, 0, 0); stageA(0, 1, 0); stageB(0, 0, 0); stageB(0, 1, 0);
  stageA(1, 0, 1); stageB(1, 0, 1);
  asm volatile("s_waitcnt vmcnt(4)" ::: "memory");
  __builtin_amdgcn_sched_barrier(0);
  __builtin_amdgcn_s_barrier();
  __builtin_amdgcn_sched_barrier(0);

  const int raBase = (wm * 128 + l16) * 64;
  const int rbBase = (wn * 64 + l16) * 64;
  const int sw = l16 & 7;

  for (int ti = 0; ti < nt; ti++) {
    const int cb = ti & 1;
    const ushort_t* as_ = As[cb];
    const ushort_t* bs_ = Bs[cb];

    // ---- phase 0: read af(ih0) + bf0(jh0); stage (t+1, A-ih1) -> buf^1
#pragma unroll
    for (int kk = 0; kk < 2; kk++) {
      int ch = ((kk * 4 + quad) ^ sw) * 8;
#pragma unroll
      for (int di = 0; di < 4; di++)
        af[kk][di] = *(const short8*)&as_[raBase + di * 1024 + ch];
#pragma unroll
      for (int dj = 0; dj < 2; dj++)
        bf0[kk][dj] = *(const short8*)&bs_[rbBase + dj * 1024 + ch];
    }
    if (ti + 1 < nt) stageA(ti + 1, 1, cb ^ 1);
    __builtin_amdgcn_sched_barrier(0);
    __builtin_amdgcn_s_barrier();
    __builtin_amdgcn_sched_barrier(0);
    __builtin_amdgcn_s_setprio(1);
#pragma unroll
    for (int di = 0; di < 4; di++)
#pragma unroll
      for (int dj = 0; dj < 2; dj++)
#pragma unroll
        for (int kk = 0; kk < 2; kk++)
          acc[di][dj] = __builtin_amdgcn_mfma_f32_16x16x32_bf16(af[kk][di], bf0[kk][dj], acc[di][dj], 0, 0, 0);
    __builtin_amdgcn_s_setprio(0);
    __builtin_amdgcn_sched_barrier(0);
    __builtin_amdgcn_s_barrier();
    __builtin_amdgcn_sched_barrier(0);

    // ---- phase 1: read bf1(jh1); stage (t+1, B-jh1) -> buf^1
#pragma unroll
    for (int kk = 0; kk < 2; kk++) {
      int ch = ((kk * 4 + quad) ^ sw) * 8;
#pragma unroll
      for (int dj = 0; dj < 2; dj++)
        bf1[kk][dj] = *(const short8*)&bs_[rbBase + (2 + dj) * 1024 + ch];
    }
    if (ti + 1 < nt) stageB(ti + 1, 1, cb ^ 1);
    __builtin_amdgcn_sched_barrier(0);
    __builtin_amdgcn_s_barrier();
    __builtin_amdgcn_sched_barrier(0);
    __builtin_amdgcn_s_setprio(1);
#pragma unroll
    for (int di = 0; di < 4; di++)
#pragma unroll
      for (int dj = 0; dj < 2; dj++)
#pragma unroll
        for (int kk = 0; kk < 2; kk++)
          acc[di][2 + dj] = __builtin_amdgcn_mfma_f32_16x16x32_bf16(af[kk][di], bf1[kk][dj], acc[di][2 + dj], 0, 0, 0);
    __builtin_amdgcn_s_setprio(0);
    __builtin_amdgcn_sched_barrier(0);
    __builtin_amdgcn_s_barrier();
    __builtin_amdgcn_sched_barrier(0);

    // ---- phase 2: read af(ih1); stage (t+2, A-ih0) -> buf (dead since p1)
#pragma unroll
    for (int kk = 0; kk < 2; kk++) {
      int ch = ((kk * 4 + quad) ^ sw) * 8;
#pragma unroll
      for (int di = 0; di < 4; di++)
        af[kk][di] = *(const short8*)&as_[raBase + (4 + di) * 1024 + ch];
    }
    if (ti + 2 < nt) stageA(ti + 2, 0, cb);
    __builtin_amdgcn_sched_barrier(0);
    __builtin_amdgcn_s_barrier();
    __builtin_amdgcn_sched_barrier(0);
    __builtin_amdgcn_s_setprio(1);
#pragma unroll
    for (int di = 0; di < 4; di++)
#pragma unroll
      for (int dj = 0; dj < 2; dj++)
#pragma unroll
        for (int kk = 0; kk < 2; kk++)
          acc[4 + di][dj] = __builtin_amdgcn_mfma_f32_16x16x32_bf16(af[kk][di], bf0[kk][dj], acc[4 + di][dj], 0, 0, 0);
    __builtin_amdgcn_s_setprio(0);
    __builtin_amdgcn_sched_barrier(0);
    __builtin_amdgcn_s_barrier();
    __builtin_amdgcn_sched_barrier(0);

    // ---- phase 3: no reads; stage (t+2, B-jh0) -> buf (dead since p1);
    //      counted vmcnt publishes tile t+1 (4 newer loads in flight)
    if (ti + 2 < nt) stageB(ti + 2, 0, cb);
    __builtin_amdgcn_sched_barrier(0);
    __builtin_amdgcn_s_barrier();
    __builtin_amdgcn_sched_barrier(0);
    __builtin_amdgcn_s_setprio(1);
#pragma unroll
    for (int di = 0; di < 4; di++)
#pragma unroll
      for (int dj = 0; dj < 2; dj++)
#pragma unroll
        for (int kk = 0; kk < 2; kk++)
          acc[4 + di][2 + dj] = __builtin_amdgcn_mfma_f32_16x16x32_bf16(af[kk][di], bf1[kk][dj], acc[4 + di][2 + dj], 0, 0, 0);
    __builtin_amdgcn_s_setprio(0);
    if (ti + 2 < nt) {
      asm volatile("s_waitcnt vmcnt(4)" ::: "memory");
    } else if (ti + 1 < nt) {
      asm volatile("s_waitcnt vmcnt(0)" ::: "memory");
    }
    __builtin_amdgcn_sched_barrier(0);
    __builtin_amdgcn_s_barrier();
    __builtin_amdgcn_sched_barrier(0);
  }

#pragma unroll
  for (int i = 0; i < 8; i++)
#pragma unroll
    for (int j = 0; j < 4; j++)
#pragma unroll
      for (int r = 0; r < 4; r++) {
        long rr = bm + wm * 128 + i * 16 + quad * 4 + r;
        long cc = bn + wn * 64 + j * 16 + l16;
        store_out(&C[rr * N + cc], acc[i][j][r]);
      }
}

// ---------------- RMSNorm + RoPE, in place on bf16 qkv ----------------
__global__ __launch_bounds__(256) void rmsnorm_rope(
    ushort_t* __restrict__ qkv, const int* __restrict__ positions,
    const float* __restrict__ qw, const float* __restrict__ kw) {
  int gw = blockIdx.x * 4 + (threadIdx.x >> 6);
  int lane = threadIdx.x & 63;
  int bs = gw / 20, h = gw % 20;
  ushort_t* src = qkv + (long)bs * 3072 + h * 128;
  float x0 = bf2f(src[lane]), x1 = bf2f(src[lane + 64]);
  float ss = x0 * x0 + x1 * x1;
#pragma unroll
  for (int off = 32; off; off >>= 1) ss += __shfl_xor(ss, off);
  float r = rsqrtf(ss * (1.0f / 128.0f) + EPS_);
  const float* w = (h < 16) ? qw : kw;
  x0 = x0 * r * w[lane];
  x1 = x1 * r * w[lane + 64];
  float pos = (float)positions[bs];
  float inv_freq = powf(THETA_, -(float)lane * (1.0f / 64.0f));
  float f = pos * inv_freq;
  float sn, cs;
  sincosf(f, &sn, &cs);
  float o0 = x0 * cs - x1 * sn;
  float o1 = x1 * cs + x0 * sn;
  src[lane] = f2bf(o0);
  src[lane + 64] = f2bf(o1);
}

// ------ V transpose: qkv [B,S,3072] v-columns -> Vt [B,NKV,D,S] ------
__global__ __launch_bounds__(256) void transpose_v(
    const ushort_t* __restrict__ qkv, ushort_t* __restrict__ Vt) {
  __shared__ ushort_t tile[64][65];
  int bh = blockIdx.z; // b*NKV + hk
  int s0 = blockIdx.x * 64, d0 = blockIdx.y * 64;
  int b = bh >> 2, hk = bh & 3;
  int tx = threadIdx.x & 63, ty = threadIdx.x >> 6; // ty 0..3
#pragma unroll
  for (int j = 0; j < 16; j++) {
    int sl = j * 4 + ty;
    tile[sl][tx] = qkv[(long)(b * Ss + s0 + sl) * 3072 + 2560 + hk * 128 + d0 + tx];
  }
  __syncthreads();
  const long vtbase = (long)bh * Dd * Ss;
#pragma unroll
  for (int j = 0; j < 16; j++) {
    int dl = j * 4 + ty;
    Vt[vtbase + (long)(d0 + dl) * Ss + s0 + tx] = tile[tx][dl];
  }
}

// ---------------- flash attention (R6 state: 86us, verified) ----------------
__global__ __launch_bounds__(512) void flash_attn(
    const ushort_t* __restrict__ qkv, const ushort_t* __restrict__ Vt,
    ushort_t* __restrict__ ctx) {
  __shared__ __align__(16) ushort_t Ks[2][64 * 128];   // [kvrow][d] (16 chunks/row)
  __shared__ __align__(16) ushort_t Vs[2][128 * 64];   // [d][kv]    (8 chunks/row)
  __shared__ __align__(16) ushort_t Ps[8][16 * 64];    // per-wave P [q][key]
  const int qt = blockIdx.x, h = blockIdx.y, b = blockIdx.z;
  const int hk = h >> 2;
  const int t = threadIdx.x, wave = t >> 6, lane = t & 63;
  const int quad = lane >> 4, l16 = lane & 15;

  const ushort_t* qp = qkv + (long)(b * Ss + qt * 128) * 3072 + h * 128;
  const ushort_t* kp = qkv + (long)(b * Ss) * 3072 + 2048 + hk * 128;
  const ushort_t* vp = Vt + ((long)(b * NKV + hk) * Dd) * Ss;

  auto stage = [&](int kt, int bi) {
    const int k0 = kt * 64;
#pragma unroll
    for (int it = 0; it < 2; it++) {
      int tt = t + it * 512;
      int row = tt >> 4, cl = tt & 15, cg = cl ^ (row & 15);
      gload_lds16(kp + (long)(k0 + row) * 3072 + cg * 8, &Ks[bi][tt * 8]);
    }
#pragma unroll
    for (int it = 0; it < 2; it++) {
      int tt = t + it * 512;
      int row = tt >> 3, cl = tt & 7, cg = cl ^ (row & 7);
      gload_lds16(vp + (long)row * Ss + k0 + cg * 8, &Vs[bi][tt * 8]);
    }
  };

  stage(0, 0);

  short8 qf[4];
  {
    const ushort_t* qrow = qp + (long)(wave * 16 + l16) * 3072 + quad * 8;
#pragma unroll
    for (int kc = 0; kc < 4; kc++)
      qf[kc] = *(const short8*)(qrow + kc * 32);
  }

  float m_i = -1e30f;   // running max for q = l16 (replicated across quads)
  float l_acc = 0.f;    // per-lane partial denom (q = l16, this quad's keys)
  f32x4 o[8] = {};      // output: q = quad*4+r, d = dt*16+l16

  asm volatile("s_waitcnt vmcnt(0)" ::: "memory");
  __syncthreads();

  int cur = 0;
  for (int kt = 0; kt < Ss / 64; kt++) {
    if (kt + 1 < Ss / 64) stage(kt + 1, cur ^ 1);

    // S^T: sa[nt][r] = S[key = nt*16 + quad*4 + r][q = l16]
    f32x4 sa[4] = {};
    __builtin_amdgcn_s_setprio(1);
#pragma unroll
    for (int kc = 0; kc < 4; kc++) {
#pragma unroll
      for (int nt = 0; nt < 4; nt++) {
        int brow = nt * 16 + l16;
        short8 kfr = *(const short8*)&Ks[cur][brow * 128 + (((kc * 4 + quad) ^ (brow & 15)) * 8)];
        sa[nt] = __builtin_amdgcn_mfma_f32_16x16x32_bf16(kfr, qf[kc], sa[nt], 0, 0, 0);
      }
    }
    __builtin_amdgcn_s_setprio(0);

    float pmax = sa[0][0];
#pragma unroll
    for (int nt = 0; nt < 4; nt++)
#pragma unroll
      for (int r = 0; r < 4; r++) pmax = fmaxf(pmax, sa[nt][r]);

    bool upd = __any(pmax > m_i + THR_RAW_);
    float alpha = 1.0f;
    if (upd) {
      float mx = fmaxf(pmax, __shfl_xor(pmax, 16));
      mx = fmaxf(mx, __shfl_xor(mx, 32));        // true row max, all quads
      float mnew = fmaxf(m_i, mx);
      alpha = __builtin_amdgcn_exp2f((m_i - mnew) * C2_);
      m_i = mnew;
      l_acc *= alpha;
    }

    float mC2 = m_i * C2_;
    float rs = 0.f;
#pragma unroll
    for (int nt = 0; nt < 4; nt++) {
      int cbase = l16 * 64 + ((nt * 2 + (quad >> 1)) ^ (l16 & 7)) * 8 + (quad & 1) * 4;
#pragma unroll
      for (int r = 0; r < 4; r++) {
        float p = __builtin_amdgcn_exp2f(__builtin_fmaf(sa[nt][r], C2_, -mC2));
        rs += p;
        union { float f; unsigned u; } pv; pv.f = p;
        Ps[wave][cbase + r] = (ushort_t)((pv.u + 0x8000u) >> 16);
      }
    }
    l_acc += rs;

    if (upd) {
      float ar0 = __shfl(alpha, quad * 4 + 0);
      float ar1 = __shfl(alpha, quad * 4 + 1);
      float ar2 = __shfl(alpha, quad * 4 + 2);
      float ar3 = __shfl(alpha, quad * 4 + 3);
#pragma unroll
      for (int dt = 0; dt < 8; dt++) {
        o[dt][0] *= ar0; o[dt][1] *= ar1; o[dt][2] *= ar2; o[dt][3] *= ar3;
      }
    }
    asm volatile("s_waitcnt lgkmcnt(0)" ::: "memory");

    __builtin_amdgcn_s_setprio(1);
#pragma unroll
    for (int kc = 0; kc < 2; kc++) {
      int arow = l16;
      short8 af = *(const short8*)&Ps[wave][arow * 64 + (((kc * 4 + quad) ^ (arow & 7)) * 8)];
#pragma unroll
      for (int dt = 0; dt < 8; dt++) {
        int brow = dt * 16 + l16;
        short8 bfr = *(const short8*)&Vs[cur][brow * 64 + (((kc * 4 + quad) ^ (brow & 7)) * 8)];
        o[dt] = __builtin_amdgcn_mfma_f32_16x16x32_bf16(af, bfr, o[dt], 0, 0, 0);
      }
    }
    __builtin_amdgcn_s_setprio(0);

    asm volatile("s_waitcnt vmcnt(0)" ::: "memory");
    __syncthreads();
    cur ^= 1;
  }

  float lt = l_acc + __shfl_xor(l_acc, 16);
  lt += __shfl_xor(lt, 32);
  float linv = 1.0f / lt;
  float lr0 = __shfl(linv, quad * 4 + 0);
  float lr1 = __shfl(linv, quad * 4 + 1);
  float lr2 = __shfl(linv, quad * 4 + 2);
  float lr3 = __shfl(linv, quad * 4 + 3);
  const long obase = (long)(b * Ss + qt * 128 + wave * 16) * (NH * Dd) + h * Dd;
#pragma unroll
  for (int dt = 0; dt < 8; dt++) {
    int col = dt * 16 + l16;
    ctx[obase + (long)(quad * 4 + 0) * (NH * Dd) + col] = f2bf(o[dt][0] * lr0);
    ctx[obase + (long)(quad * 4 + 1) * (NH * Dd) + col] = f2bf(o[dt][1] * lr1);
    ctx[obase + (long)(quad * 4 + 2) * (NH * Dd) + col] = f2bf(o[dt][2] * lr2);
    ctx[obase + (long)(quad * 4 + 3) * (NH * Dd) + col] = f2bf(o[dt][3] * lr3);
  }
}

extern "C" void kernel_launch(void* const* d_in, const int* in_sizes, int n_in,
                              void* d_out, int out_size, void* d_ws, size_t ws_size,
                              hipStream_t stream) {
  const float* hidden = (const float*)d_in[0];
  const int* positions = (const int*)d_in[1];
  const float* Wq = (const float*)d_in[2];
  const float* Wk = (const float*)d_in[3];
  const float* Wv = (const float*)d_in[4];
  const float* Wo = (const float*)d_in[5];
  const float* qw = (const float*)d_in[6];
  const float* kw = (const float*)d_in[7];
  float* out = (float*)d_out;

  // 64 MB workspace layout:
  char* ws = (char*)d_ws;
  ushort_t* Xbf = (ushort_t*)(ws);                    // 16 MB (4096x2048 bf16)
  ushort_t* WqkvT = (ushort_t*)(ws + (16l << 20));    // 12 MB (3072x2048 bf16)
  ushort_t* WoT = (ushort_t*)(ws + (28l << 20));      //  8 MB (2048x2048 bf16)
  ushort_t* qkvb = (ushort_t*)(ws + (36l << 20));     // 24 MB (4096x3072 bf16)
  ushort_t* Vt = (ushort_t*)(ws + (60l << 20));       //  4 MB (B,NKV,D,S bf16)
  ushort_t* ctx = Xbf;                                // reuse (dead after GEMM1)

  const long nX = (long)Bb * Ss * HID;
  convert_f32_bf16<<<(unsigned)(nX / 4 / 256), 256, 0, stream>>>(hidden, Xbf, nX);
  transpose_f32_bf16<<<dim3(2048 / 32, 2048 / 32), 256, 0, stream>>>(Wq, WqkvT, 2048, 2048);
  transpose_f32_bf16<<<dim3(512 / 32, 2048 / 32), 256, 0, stream>>>(Wk, WqkvT + (long)2048 * 2048, 2048, 512);
  transpose_f32_bf16<<<dim3(512 / 32, 2048 / 32), 256, 0, stream>>>(Wv, WqkvT + (long)2560 * 2048, 2048, 512);
  transpose_f32_bf16<<<dim3(2048 / 32, 2048 / 32), 256, 0, stream>>>(Wo, WoT, 2048, 2048);

  // GEMM1 on the 8-phase 256^2 kernel: grid 12x16 = 192 blocks (%8==0)
  gemm256_bt<ushort_t><<<dim3(3072 / 256, 4096 / 256), 512, 0, stream>>>(Xbf, WqkvT, qkvb, 4096, 3072, 2048);

  rmsnorm_rope<<<(Bb * Ss * 20) / 4, 256, 0, stream>>>(qkvb, positions, qw, kw);
  transpose_v<<<dim3(Ss / 64, Dd / 64, Bb * NKV), 256, 0, stream>>>(qkvb, Vt);

  flash_attn<<<dim3(Ss / 128, NH, Bb), 512, 0, stream>>>(qkvb, Vt, ctx);

  gemm_bt<float><<<dim3(2048 / 128, 4096 / 128), 256, 0, stream>>>(ctx, WoT, out, 4096, 2048, 2048);
}

// Round 8
// 339.407 us; speedup vs baseline: 1.2532x; 1.0308x over previous
//
#include <hip/hip_runtime.h>

typedef unsigned short ushort_t;
typedef __attribute__((ext_vector_type(8))) short short8;
typedef __attribute__((ext_vector_type(4))) ushort_t ushort4_t;
typedef __attribute__((ext_vector_type(4))) float f32x4;

#define Bb 2
#define Ss 2048
#define HID 2048
#define NH 16
#define NKV 4
#define Dd 128
constexpr float EPS_ = 1e-6f;
constexpr float THETA_ = 1000000.0f;
constexpr float SCALE_ = 0.08838834764831845f; // 128^-0.5
constexpr float C2_ = 0.12753785f;             // SCALE * log2(e)
constexpr float THR_RAW_ = 23.5f;              // 3 / C2_: defer-max threshold (P <= 8)

__device__ __forceinline__ ushort_t f2bf(float x) {
  union { float f; unsigned u; } v; v.f = x;
  unsigned r = (v.u + 0x7fffu + ((v.u >> 16) & 1u)) >> 16;
  return (ushort_t)r;
}
__device__ __forceinline__ float bf2f(ushort_t u) {
  union { unsigned u; float f; } v; v.u = ((unsigned)u) << 16;
  return v.f;
}

typedef const __attribute__((address_space(1))) void* gas1_t;
typedef __attribute__((address_space(3))) void* las3_t;
__device__ __forceinline__ void gload_lds16(const void* g, void* l) {
  __builtin_amdgcn_global_load_lds((gas1_t)g, (las3_t)l, 16, 0, 0);
}

__device__ __forceinline__ void store_out(float* p, float v) { *p = v; }
__device__ __forceinline__ void store_out(ushort_t* p, float v) { *p = f2bf(v); }

// ---------------- fp32 -> bf16 straight convert (8 elems/thread) ----------------
__global__ __launch_bounds__(256) void convert_f32_bf16(
    const float* __restrict__ src, ushort_t* __restrict__ dst, long n) {
  long i = ((long)blockIdx.x * 256 + threadIdx.x) * 8;
  if (i + 7 < n) {
    float4 v0 = *(const float4*)(src + i);
    float4 v1 = *(const float4*)(src + i + 4);
    ushort4_t a, b;
    a[0] = f2bf(v0.x); a[1] = f2bf(v0.y); a[2] = f2bf(v0.z); a[3] = f2bf(v0.w);
    b[0] = f2bf(v1.x); b[1] = f2bf(v1.y); b[2] = f2bf(v1.z); b[3] = f2bf(v1.w);
    *(ushort4_t*)(dst + i) = a;
    *(ushort4_t*)(dst + i + 4) = b;
  }
}

// ------- merged weight transposes: fp32 (R x C) -> bf16 (C x R), 4 weights -------
// 1D grid of 10240 tile-blocks: [0,4096) Wq | [4096,5120) Wk | [5120,6144) Wv |
// [6144,10240) Wo. All R=2048; C=2048/512/512/2048. Block-uniform decode.
__global__ __launch_bounds__(256) void transpose_weights(
    const float* __restrict__ Wq, const float* __restrict__ Wk,
    const float* __restrict__ Wv, const float* __restrict__ Wo,
    ushort_t* __restrict__ WqkvT, ushort_t* __restrict__ WoT) {
  __shared__ float tile[32][33];
  unsigned id = blockIdx.x;
  const float* src;
  ushort_t* dst;
  int C, tX;
  if (id < 4096u) {
    src = Wq; dst = WqkvT; C = 2048; tX = 64;
  } else if (id < 5120u) {
    id -= 4096u; src = Wk; dst = WqkvT + (long)2048 * 2048; C = 512; tX = 16;
  } else if (id < 6144u) {
    id -= 5120u; src = Wv; dst = WqkvT + (long)2560 * 2048; C = 512; tX = 16;
  } else {
    id -= 6144u; src = Wo; dst = WoT; C = 2048; tX = 64;
  }
  const int R = 2048;
  int c0 = (id % tX) * 32, r0 = (id / tX) * 32;
  int tx = threadIdx.x & 31, ty = threadIdx.x >> 5; // ty 0..7
#pragma unroll
  for (int j = 0; j < 4; j++)
    tile[ty + j * 8][tx] = src[(long)(r0 + ty + j * 8) * C + c0 + tx];
  __syncthreads();
#pragma unroll
  for (int j = 0; j < 4; j++)
    dst[(long)(c0 + ty + j * 8) * R + r0 + tx] = f2bf(tile[tx][ty + j * 8]);
}

// ---------------- bf16 GEMM: C[M,N] = A[M,K] * Bt[N,K]^T ----------------
// m97 recipe: 128x128x32 tiles, 4 waves each 64x64, global_load_lds width 16.
// Kept for GEMM2 (2048 cols -> 256^2 tile would leave half the CUs idle).
template <typename OutT>
__global__ __launch_bounds__(256) void gemm_bt(
    const ushort_t* __restrict__ A, const ushort_t* __restrict__ Bt,
    OutT* __restrict__ C, int M, int N, int K) {
  __shared__ __align__(16) ushort_t As[128 * 32];
  __shared__ __align__(16) ushort_t Bs[128 * 32];
  const int t = threadIdx.x;
  const int wave = t >> 6, lane = t & 63;
  const int wr = wave >> 1, wc = wave & 1;
  const int quad = lane >> 4, l16 = lane & 15;

  unsigned gx = gridDim.x;
  unsigned nwg = gx * gridDim.y;
  unsigned lin = blockIdx.y * gx + blockIdx.x;
  if ((nwg & 7u) == 0u) {
    unsigned cpx = nwg >> 3;
    lin = (lin & 7u) * cpx + (lin >> 3);
  }
  const long bm = (long)(lin / gx) * 128;
  const long bn = (long)(lin % gx) * 128;

  f32x4 acc[4][4] = {};

  const int srow = t >> 2, schunk = t & 3;
  const ushort_t* aSrc = A + (bm + srow) * (long)K + schunk * 8;
  const ushort_t* bSrc = Bt + (bn + srow) * (long)K + schunk * 8;
  const int ldsOff = srow * 32 + schunk * 8;

  for (int k0 = 0; k0 < K; k0 += 32) {
    __syncthreads();
    gload_lds16(aSrc + k0, &As[ldsOff]);
    gload_lds16(aSrc + (long)64 * K + k0, &As[ldsOff + 64 * 32]);
    gload_lds16(bSrc + k0, &Bs[ldsOff]);
    gload_lds16(bSrc + (long)64 * K + k0, &Bs[ldsOff + 64 * 32]);
    __syncthreads();
    short8 af[4], bf[4];
#pragma unroll
    for (int i = 0; i < 4; i++) {
      af[i] = *(const short8*)&As[(wr * 64 + i * 16 + l16) * 32 + quad * 8];
      bf[i] = *(const short8*)&Bs[(wc * 64 + i * 16 + l16) * 32 + quad * 8];
    }
#pragma unroll
    for (int i = 0; i < 4; i++)
#pragma unroll
      for (int j = 0; j < 4; j++)
        acc[i][j] = __builtin_amdgcn_mfma_f32_16x16x32_bf16(af[i], bf[j], acc[i][j], 0, 0, 0);
  }
#pragma unroll
  for (int i = 0; i < 4; i++)
#pragma unroll
    for (int j = 0; j < 4; j++)
#pragma unroll
      for (int r = 0; r < 4; r++) {
        long rr = bm + wr * 64 + i * 16 + quad * 4 + r;
        long cc = bn + wc * 64 + j * 16 + l16;
        store_out(&C[rr * N + cc], acc[i][j][r]);
      }
}

// ---------------- 256x256 8-phase bf16 GEMM (T3+T4+T5) ----------------
// R7-verified. 8 waves (2M x 4N), BK=64, LDS 128KB. Counted vmcnt(4), raw
// s_barrier + sched_barrier(0), setprio around MFMA clusters.
template <typename OutT>
__global__ __launch_bounds__(512) void gemm256_bt(
    const ushort_t* __restrict__ A, const ushort_t* __restrict__ Bt,
    OutT* __restrict__ C, int M, int N, int K) {
  __shared__ __align__(16) ushort_t As[2][256 * 64];
  __shared__ __align__(16) ushort_t Bs[2][256 * 64];
  const int t = threadIdx.x;
  const int wave = t >> 6, lane = t & 63;
  const int wm = wave >> 2, wn = wave & 3;
  const int quad = lane >> 4, l16 = lane & 15;

  unsigned gx = gridDim.x;
  unsigned nwg = gx * gridDim.y;
  unsigned lin = blockIdx.y * gx + blockIdx.x;
  if ((nwg & 7u) == 0u) {
    unsigned cpx = nwg >> 3;
    lin = (lin & 7u) * cpx + (lin >> 3);
  }
  const long bm = (long)(lin / gx) * 256;
  const long bn = (long)(lin % gx) * 256;

  auto stageA = [&](int kt, int ih, int bi) {
    const int k0 = kt * 64;
#pragma unroll
    for (int it = 0; it < 2; it++) {
      int ci = t + it * 512;
      int lr = ci >> 3, cl = ci & 7;
      int row = ((lr & 64) << 1) | (ih << 6) | (lr & 63);
      int cg = cl ^ (row & 7);
      gload_lds16(A + (bm + row) * (long)K + k0 + cg * 8, &As[bi][row * 64 + cl * 8]);
    }
  };
  auto stageB = [&](int kt, int jh, int bi) {
    const int k0 = kt * 64;
#pragma unroll
    for (int it = 0; it < 2; it++) {
      int ci = t + it * 512;
      int lr = ci >> 3, cl = ci & 7;
      int row = ((lr & 96) << 1) | (jh << 5) | (lr & 31);
      int cg = cl ^ (row & 7);
      gload_lds16(Bt + (bn + row) * (long)K + k0 + cg * 8, &Bs[bi][row * 64 + cl * 8]);
    }
  };

  f32x4 acc[8][4] = {};
  short8 af[2][4], bf0[2][2], bf1[2][2];

  const int nt = K >> 6;
  stageA(0, 0, 0); stageA(0, 1, 0); stageB(0, 0, 0); stageB(0, 1, 0);
  stageA(1, 0, 1); stageB(1, 0, 1);
  asm volatile("s_waitcnt vmcnt(4)" ::: "memory");
  __builtin_amdgcn_sched_barrier(0);
  __builtin_amdgcn_s_barrier();
  __builtin_amdgcn_sched_barrier(0);

  const int raBase = (wm * 128 + l16) * 64;
  const int rbBase = (wn * 64 + l16) * 64;
  const int sw = l16 & 7;

  for (int ti = 0; ti < nt; ti++) {
    const int cb = ti & 1;
    const ushort_t* as_ = As[cb];
    const ushort_t* bs_ = Bs[cb];

    // ---- phase 0
#pragma unroll
    for (int kk = 0; kk < 2; kk++) {
      int ch = ((kk * 4 + quad) ^ sw) * 8;
#pragma unroll
      for (int di = 0; di < 4; di++)
        af[kk][di] = *(const short8*)&as_[raBase + di * 1024 + ch];
#pragma unroll
      for (int dj = 0; dj < 2; dj++)
        bf0[kk][dj] = *(const short8*)&bs_[rbBase + dj * 1024 + ch];
    }
    if (ti + 1 < nt) stageA(ti + 1, 1, cb ^ 1);
    __builtin_amdgcn_sched_barrier(0);
    __builtin_amdgcn_s_barrier();
    __builtin_amdgcn_sched_barrier(0);
    __builtin_amdgcn_s_setprio(1);
#pragma unroll
    for (int di = 0; di < 4; di++)
#pragma unroll
      for (int dj = 0; dj < 2; dj++)
#pragma unroll
        for (int kk = 0; kk < 2; kk++)
          acc[di][dj] = __builtin_amdgcn_mfma_f32_16x16x32_bf16(af[kk][di], bf0[kk][dj], acc[di][dj], 0, 0, 0);
    __builtin_amdgcn_s_setprio(0);
    __builtin_amdgcn_sched_barrier(0);
    __builtin_amdgcn_s_barrier();
    __builtin_amdgcn_sched_barrier(0);

    // ---- phase 1
#pragma unroll
    for (int kk = 0; kk < 2; kk++) {
      int ch = ((kk * 4 + quad) ^ sw) * 8;
#pragma unroll
      for (int dj = 0; dj < 2; dj++)
        bf1[kk][dj] = *(const short8*)&bs_[rbBase + (2 + dj) * 1024 + ch];
    }
    if (ti + 1 < nt) stageB(ti + 1, 1, cb ^ 1);
    __builtin_amdgcn_sched_barrier(0);
    __builtin_amdgcn_s_barrier();
    __builtin_amdgcn_sched_barrier(0);
    __builtin_amdgcn_s_setprio(1);
#pragma unroll
    for (int di = 0; di < 4; di++)
#pragma unroll
      for (int dj = 0; dj < 2; dj++)
#pragma unroll
        for (int kk = 0; kk < 2; kk++)
          acc[di][2 + dj] = __builtin_amdgcn_mfma_f32_16x16x32_bf16(af[kk][di], bf1[kk][dj], acc[di][2 + dj], 0, 0, 0);
    __builtin_amdgcn_s_setprio(0);
    __builtin_amdgcn_sched_barrier(0);
    __builtin_amdgcn_s_barrier();
    __builtin_amdgcn_sched_barrier(0);

    // ---- phase 2
#pragma unroll
    for (int kk = 0; kk < 2; kk++) {
      int ch = ((kk * 4 + quad) ^ sw) * 8;
#pragma unroll
      for (int di = 0; di < 4; di++)
        af[kk][di] = *(const short8*)&as_[raBase + (4 + di) * 1024 + ch];
    }
    if (ti + 2 < nt) stageA(ti + 2, 0, cb);
    __builtin_amdgcn_sched_barrier(0);
    __builtin_amdgcn_s_barrier();
    __builtin_amdgcn_sched_barrier(0);
    __builtin_amdgcn_s_setprio(1);
#pragma unroll
    for (int di = 0; di < 4; di++)
#pragma unroll
      for (int dj = 0; dj < 2; dj++)
#pragma unroll
        for (int kk = 0; kk < 2; kk++)
          acc[4 + di][dj] = __builtin_amdgcn_mfma_f32_16x16x32_bf16(af[kk][di], bf0[kk][dj], acc[4 + di][dj], 0, 0, 0);
    __builtin_amdgcn_s_setprio(0);
    __builtin_amdgcn_sched_barrier(0);
    __builtin_amdgcn_s_barrier();
    __builtin_amdgcn_sched_barrier(0);

    // ---- phase 3
    if (ti + 2 < nt) stageB(ti + 2, 0, cb);
    __builtin_amdgcn_sched_barrier(0);
    __builtin_amdgcn_s_barrier();
    __builtin_amdgcn_sched_barrier(0);
    __builtin_amdgcn_s_setprio(1);
#pragma unroll
    for (int di = 0; di < 4; di++)
#pragma unroll
      for (int dj = 0; dj < 2; dj++)
#pragma unroll
        for (int kk = 0; kk < 2; kk++)
          acc[4 + di][2 + dj] = __builtin_amdgcn_mfma_f32_16x16x32_bf16(af[kk][di], bf1[kk][dj], acc[4 + di][2 + dj], 0, 0, 0);
    __builtin_amdgcn_s_setprio(0);
    if (ti + 2 < nt) {
      asm volatile("s_waitcnt vmcnt(4)" ::: "memory");
    } else if (ti + 1 < nt) {
      asm volatile("s_waitcnt vmcnt(0)" ::: "memory");
    }
    __builtin_amdgcn_sched_barrier(0);
    __builtin_amdgcn_s_barrier();
    __builtin_amdgcn_sched_barrier(0);
  }

#pragma unroll
  for (int i = 0; i < 8; i++)
#pragma unroll
    for (int j = 0; j < 4; j++)
#pragma unroll
      for (int r = 0; r < 4; r++) {
        long rr = bm + wm * 128 + i * 16 + quad * 4 + r;
        long cc = bn + wn * 64 + j * 16 + l16;
        store_out(&C[rr * N + cc], acc[i][j][r]);
      }
}

// ------ merged RMSNorm+RoPE (in place, Q/K heads) + V transpose ------
// blocks [0, 20480): rmsnorm_rope on qkv cols 0..2559 (20 heads)
// blocks [20480, 20992): transpose_v reading qkv cols 2560.. -> Vt
// The two halves touch disjoint data -> safe to fuse into one dispatch.
__global__ __launch_bounds__(256) void rmsnorm_rope_tv(
    ushort_t* __restrict__ qkv, const int* __restrict__ positions,
    const float* __restrict__ qw, const float* __restrict__ kw,
    ushort_t* __restrict__ Vt) {
  __shared__ ushort_t tile[64][65];
  unsigned bx = blockIdx.x;
  if (bx < 20480u) {
    int gw = bx * 4 + (threadIdx.x >> 6);
    int lane = threadIdx.x & 63;
    int bs = gw / 20, h = gw % 20;
    ushort_t* src = qkv + (long)bs * 3072 + h * 128;
    float x0 = bf2f(src[lane]), x1 = bf2f(src[lane + 64]);
    float ss = x0 * x0 + x1 * x1;
#pragma unroll
    for (int off = 32; off; off >>= 1) ss += __shfl_xor(ss, off);
    float r = rsqrtf(ss * (1.0f / 128.0f) + EPS_);
    const float* w = (h < 16) ? qw : kw;
    x0 = x0 * r * w[lane];
    x1 = x1 * r * w[lane + 64];
    float pos = (float)positions[bs];
    float inv_freq = powf(THETA_, -(float)lane * (1.0f / 64.0f));
    float f = pos * inv_freq;
    float sn, cs;
    sincosf(f, &sn, &cs);
    float o0 = x0 * cs - x1 * sn;
    float o1 = x1 * cs + x0 * sn;
    src[lane] = f2bf(o0);
    src[lane + 64] = f2bf(o1);
  } else {
    unsigned id = bx - 20480u;           // old grid dim3(32, 2, 8)
    int bxo = id & 31, byo = (id >> 5) & 1, bh = id >> 6;
    int s0 = bxo * 64, d0 = byo * 64;
    int b = bh >> 2, hk = bh & 3;
    int tx = threadIdx.x & 63, ty = threadIdx.x >> 6; // ty 0..3
#pragma unroll
    for (int j = 0; j < 16; j++) {
      int sl = j * 4 + ty;
      tile[sl][tx] = qkv[(long)(b * Ss + s0 + sl) * 3072 + 2560 + hk * 128 + d0 + tx];
    }
    __syncthreads();
    const long vtbase = (long)bh * Dd * Ss;
#pragma unroll
    for (int j = 0; j < 16; j++) {
      int dl = j * 4 + ty;
      Vt[vtbase + (long)(d0 + dl) * Ss + s0 + tx] = tile[tx][dl];
    }
  }
}

// ---------------- flash attention (R6/R7 state: ~87us, verified) ----------------
__global__ __launch_bounds__(512) void flash_attn(
    const ushort_t* __restrict__ qkv, const ushort_t* __restrict__ Vt,
    ushort_t* __restrict__ ctx) {
  __shared__ __align__(16) ushort_t Ks[2][64 * 128];   // [kvrow][d] (16 chunks/row)
  __shared__ __align__(16) ushort_t Vs[2][128 * 64];   // [d][kv]    (8 chunks/row)
  __shared__ __align__(16) ushort_t Ps[8][16 * 64];    // per-wave P [q][key]
  const int qt = blockIdx.x, h = blockIdx.y, b = blockIdx.z;
  const int hk = h >> 2;
  const int t = threadIdx.x, wave = t >> 6, lane = t & 63;
  const int quad = lane >> 4, l16 = lane & 15;

  const ushort_t* qp = qkv + (long)(b * Ss + qt * 128) * 3072 + h * 128;
  const ushort_t* kp = qkv + (long)(b * Ss) * 3072 + 2048 + hk * 128;
  const ushort_t* vp = Vt + ((long)(b * NKV + hk) * Dd) * Ss;

  auto stage = [&](int kt, int bi) {
    const int k0 = kt * 64;
#pragma unroll
    for (int it = 0; it < 2; it++) {
      int tt = t + it * 512;
      int row = tt >> 4, cl = tt & 15, cg = cl ^ (row & 15);
      gload_lds16(kp + (long)(k0 + row) * 3072 + cg * 8, &Ks[bi][tt * 8]);
    }
#pragma unroll
    for (int it = 0; it < 2; it++) {
      int tt = t + it * 512;
      int row = tt >> 3, cl = tt & 7, cg = cl ^ (row & 7);
      gload_lds16(vp + (long)row * Ss + k0 + cg * 8, &Vs[bi][tt * 8]);
    }
  };

  stage(0, 0);

  short8 qf[4];
  {
    const ushort_t* qrow = qp + (long)(wave * 16 + l16) * 3072 + quad * 8;
#pragma unroll
    for (int kc = 0; kc < 4; kc++)
      qf[kc] = *(const short8*)(qrow + kc * 32);
  }

  float m_i = -1e30f;   // running max for q = l16 (replicated across quads)
  float l_acc = 0.f;    // per-lane partial denom (q = l16, this quad's keys)
  f32x4 o[8] = {};      // output: q = quad*4+r, d = dt*16+l16

  asm volatile("s_waitcnt vmcnt(0)" ::: "memory");
  __syncthreads();

  int cur = 0;
  for (int kt = 0; kt < Ss / 64; kt++) {
    if (kt + 1 < Ss / 64) stage(kt + 1, cur ^ 1);

    // S^T: sa[nt][r] = S[key = nt*16 + quad*4 + r][q = l16]
    f32x4 sa[4] = {};
    __builtin_amdgcn_s_setprio(1);
#pragma unroll
    for (int kc = 0; kc < 4; kc++) {
#pragma unroll
      for (int nt = 0; nt < 4; nt++) {
        int brow = nt * 16 + l16;
        short8 kfr = *(const short8*)&Ks[cur][brow * 128 + (((kc * 4 + quad) ^ (brow & 15)) * 8)];
        sa[nt] = __builtin_amdgcn_mfma_f32_16x16x32_bf16(kfr, qf[kc], sa[nt], 0, 0, 0);
      }
    }
    __builtin_amdgcn_s_setprio(0);

    float pmax = sa[0][0];
#pragma unroll
    for (int nt = 0; nt < 4; nt++)
#pragma unroll
      for (int r = 0; r < 4; r++) pmax = fmaxf(pmax, sa[nt][r]);

    bool upd = __any(pmax > m_i + THR_RAW_);
    float alpha = 1.0f;
    if (upd) {
      float mx = fmaxf(pmax, __shfl_xor(pmax, 16));
      mx = fmaxf(mx, __shfl_xor(mx, 32));        // true row max, all quads
      float mnew = fmaxf(m_i, mx);
      alpha = __builtin_amdgcn_exp2f((m_i - mnew) * C2_);
      m_i = mnew;
      l_acc *= alpha;
    }

    float mC2 = m_i * C2_;
    float rs = 0.f;
#pragma unroll
    for (int nt = 0; nt < 4; nt++) {
      int cbase = l16 * 64 + ((nt * 2 + (quad >> 1)) ^ (l16 & 7)) * 8 + (quad & 1) * 4;
#pragma unroll
      for (int r = 0; r < 4; r++) {
        float p = __builtin_amdgcn_exp2f(__builtin_fmaf(sa[nt][r], C2_, -mC2));
        rs += p;
        union { float f; unsigned u; } pv; pv.f = p;
        Ps[wave][cbase + r] = (ushort_t)((pv.u + 0x8000u) >> 16);
      }
    }
    l_acc += rs;

    if (upd) {
      float ar0 = __shfl(alpha, quad * 4 + 0);
      float ar1 = __shfl(alpha, quad * 4 + 1);
      float ar2 = __shfl(alpha, quad * 4 + 2);
      float ar3 = __shfl(alpha, quad * 4 + 3);
#pragma unroll
      for (int dt = 0; dt < 8; dt++) {
        o[dt][0] *= ar0; o[dt][1] *= ar1; o[dt][2] *= ar2; o[dt][3] *= ar3;
      }
    }
    asm volatile("s_waitcnt lgkmcnt(0)" ::: "memory");

    __builtin_amdgcn_s_setprio(1);
#pragma unroll
    for (int kc = 0; kc < 2; kc++) {
      int arow = l16;
      short8 af = *(const short8*)&Ps[wave][arow * 64 + (((kc * 4 + quad) ^ (arow & 7)) * 8)];
#pragma unroll
      for (int dt = 0; dt < 8; dt++) {
        int brow = dt * 16 + l16;
        short8 bfr = *(const short8*)&Vs[cur][brow * 64 + (((kc * 4 + quad) ^ (brow & 7)) * 8)];
        o[dt] = __builtin_amdgcn_mfma_f32_16x16x32_bf16(af, bfr, o[dt], 0, 0, 0);
      }
    }
    __builtin_amdgcn_s_setprio(0);

    asm volatile("s_waitcnt vmcnt(0)" ::: "memory");
    __syncthreads();
    cur ^= 1;
  }

  float lt = l_acc + __shfl_xor(l_acc, 16);
  lt += __shfl_xor(lt, 32);
  float linv = 1.0f / lt;
  float lr0 = __shfl(linv, quad * 4 + 0);
  float lr1 = __shfl(linv, quad * 4 + 1);
  float lr2 = __shfl(linv, quad * 4 + 2);
  float lr3 = __shfl(linv, quad * 4 + 3);
  const long obase = (long)(b * Ss + qt * 128 + wave * 16) * (NH * Dd) + h * Dd;
#pragma unroll
  for (int dt = 0; dt < 8; dt++) {
    int col = dt * 16 + l16;
    ctx[obase + (long)(quad * 4 + 0) * (NH * Dd) + col] = f2bf(o[dt][0] * lr0);
    ctx[obase + (long)(quad * 4 + 1) * (NH * Dd) + col] = f2bf(o[dt][1] * lr1);
    ctx[obase + (long)(quad * 4 + 2) * (NH * Dd) + col] = f2bf(o[dt][2] * lr2);
    ctx[obase + (long)(quad * 4 + 3) * (NH * Dd) + col] = f2bf(o[dt][3] * lr3);
  }
}

extern "C" void kernel_launch(void* const* d_in, const int* in_sizes, int n_in,
                              void* d_out, int out_size, void* d_ws, size_t ws_size,
                              hipStream_t stream) {
  const float* hidden = (const float*)d_in[0];
  const int* positions = (const int*)d_in[1];
  const float* Wq = (const float*)d_in[2];
  const float* Wk = (const float*)d_in[3];
  const float* Wv = (const float*)d_in[4];
  const float* Wo = (const float*)d_in[5];
  const float* qw = (const float*)d_in[6];
  const float* kw = (const float*)d_in[7];
  float* out = (float*)d_out;

  // 64 MB workspace layout:
  char* ws = (char*)d_ws;
  ushort_t* Xbf = (ushort_t*)(ws);                    // 16 MB (4096x2048 bf16)
  ushort_t* WqkvT = (ushort_t*)(ws + (16l << 20));    // 12 MB (3072x2048 bf16)
  ushort_t* WoT = (ushort_t*)(ws + (28l << 20));      //  8 MB (2048x2048 bf16)
  ushort_t* qkvb = (ushort_t*)(ws + (36l << 20));     // 24 MB (4096x3072 bf16)
  ushort_t* Vt = (ushort_t*)(ws + (60l << 20));       //  4 MB (B,NKV,D,S bf16)
  ushort_t* ctx = Xbf;                                // reuse (dead after GEMM1)

  const long nX = (long)Bb * Ss * HID;
  convert_f32_bf16<<<(unsigned)(nX / 8 / 256), 256, 0, stream>>>(hidden, Xbf, nX);
  transpose_weights<<<10240, 256, 0, stream>>>(Wq, Wk, Wv, Wo, WqkvT, WoT);

  // GEMM1 on the 8-phase 256^2 kernel: grid 12x16 = 192 blocks (%8==0)
  gemm256_bt<ushort_t><<<dim3(3072 / 256, 4096 / 256), 512, 0, stream>>>(Xbf, WqkvT, qkvb, 4096, 3072, 2048);

  rmsnorm_rope_tv<<<20480 + 512, 256, 0, stream>>>(qkvb, positions, qw, kw, Vt);

  flash_attn<<<dim3(Ss / 128, NH, Bb), 512, 0, stream>>>(qkvb, Vt, ctx);

  gemm_bt<float><<<dim3(2048 / 128, 4096 / 128), 256, 0, stream>>>(ctx, WoT, out, 4096, 2048, 2048);
}